// Round 5
// baseline (101.555 us; speedup 1.0000x reference)
//
#include <hip/hip_runtime.h>

// Shapes: B=4, N1=N2=128, D=256, R=4, E=D/2=128
// Pipeline:
//   A: h1p/h2 projections + W2 pre-swizzle  [one kernel, fp32 32x64 tiles]
//   B: scores via bf16 MFMA (A-fragments built in registers, no k-loop barriers)
//   C: softmax + rel
//   D: final MLP  [fp32 32x64-tile GEMM, split-K x4 + reduce]

typedef __bf16 bf16x8 __attribute__((ext_vector_type(8)));
typedef float f32x16 __attribute__((ext_vector_type(16)));

#define RS 268

static __device__ __forceinline__ ushort f2b(float f) {
  __bf16 h = (__bf16)f;
  return __builtin_bit_cast(ushort, h);
}

// ---------------- fp32 32x64-tile GEMM core (micro 2x4, KC=32) ----------------
template<int KBLK>
static __device__ __forceinline__ void gemm32x64_body(
    const float* __restrict__ A, const float* __restrict__ W,
    float* __restrict__ Cout, int K, int N, int rt, int ct, int k0)
{
  int t = threadIdx.x;
  int tm2 = t >> 4;
  int tn4 = t & 15;
  int arow = t >> 3;
  int akq = (t & 7) * 4;
  int bk = t >> 4;
  int bn4 = (t & 15) * 4;
  __shared__ __align__(16) float As[32][33];
  __shared__ __align__(16) float Bs[32][64];

  const float* Ab = A + (size_t)(rt * 32 + arow) * K + k0;
  const float* Wb = W + (size_t)k0 * N + ct * 64 + bn4;

  float4 pa = *(const float4*)&Ab[akq];
  float4 pb0 = *(const float4*)&Wb[(size_t)bk * N];
  float4 pb1 = *(const float4*)&Wb[(size_t)(bk + 16) * N];

  float acc[2][4];
  #pragma unroll
  for (int i = 0; i < 2; ++i)
    #pragma unroll
    for (int j = 0; j < 4; ++j) acc[i][j] = 0.f;

  for (int kc = 0; kc < KBLK; kc += 32) {
    __syncthreads();
    As[akq + 0][arow] = pa.x;
    As[akq + 1][arow] = pa.y;
    As[akq + 2][arow] = pa.z;
    As[akq + 3][arow] = pa.w;
    *(float4*)&Bs[bk][bn4] = pb0;
    *(float4*)&Bs[bk + 16][bn4] = pb1;
    __syncthreads();
    if (kc + 32 < KBLK) {
      pa  = *(const float4*)&Ab[kc + 32 + akq];
      pb0 = *(const float4*)&Wb[(size_t)(kc + 32 + bk) * N];
      pb1 = *(const float4*)&Wb[(size_t)(kc + 32 + bk + 16) * N];
    }
    #pragma unroll
    for (int kk = 0; kk < 32; ++kk) {
      float2 a = *(const float2*)&As[kk][tm2 * 2];
      float4 w = *(const float4*)&Bs[kk][tn4 * 4];
      acc[0][0] = fmaf(a.x, w.x, acc[0][0]); acc[0][1] = fmaf(a.x, w.y, acc[0][1]);
      acc[0][2] = fmaf(a.x, w.z, acc[0][2]); acc[0][3] = fmaf(a.x, w.w, acc[0][3]);
      acc[1][0] = fmaf(a.y, w.x, acc[1][0]); acc[1][1] = fmaf(a.y, w.y, acc[1][1]);
      acc[1][2] = fmaf(a.y, w.z, acc[1][2]); acc[1][3] = fmaf(a.y, w.w, acc[1][3]);
    }
  }

  int col = ct * 64 + tn4 * 4;
  #pragma unroll
  for (int qm = 0; qm < 2; ++qm) {
    int row = rt * 32 + tm2 * 2 + qm;
    float4 ov = make_float4(acc[qm][0], acc[qm][1], acc[qm][2], acc[qm][3]);
    *(float4*)&Cout[(size_t)row * N + col] = ov;
  }
}

template<int KBLK>
__global__ __launch_bounds__(256) void gemm_part(
    const float* __restrict__ A, const float* __restrict__ W,
    float* __restrict__ part, int K, int N, int M)
{
  int kp = blockIdx.z;
  gemm32x64_body<KBLK>(A, W, part + (size_t)kp * M * N, K, N,
                       blockIdx.y, blockIdx.x, kp * KBLK);
}

template<int P>
__global__ __launch_bounds__(256) void reduce_bias_act(
    const float* __restrict__ part, const float* __restrict__ bias,
    float* __restrict__ C, int MN, int N, int act)
{
  int idx4 = (blockIdx.x * 256 + threadIdx.x) * 4;
  if (idx4 >= MN) return;
  float4 s = *(const float4*)&part[idx4];
  #pragma unroll
  for (int p = 1; p < P; ++p) {
    float4 v = *(const float4*)&part[(size_t)p * MN + idx4];
    s.x += v.x; s.y += v.y; s.z += v.z; s.w += v.w;
  }
  float4 bv = *(const float4*)&bias[idx4 & (N - 1)];
  s.x += bv.x; s.y += bv.y; s.z += bv.z; s.w += bv.w;
  if (act) {
    s.x = fmaxf(s.x, 0.f); s.y = fmaxf(s.y, 0.f);
    s.z = fmaxf(s.z, 0.f); s.w = fmaxf(s.w, 0.f);
  }
  *(float4*)&C[idx4] = s;
}

// ---------------- projection (z<32) + W2 pre-swizzle (z==32) ----------------
__global__ __launch_bounds__(256) void k_proj_w2(
    const float* __restrict__ f1, const float* __restrict__ f2,
    const float* __restrict__ W1, const float* __restrict__ b1,
    const float* __restrict__ W2, ushort* __restrict__ W2swz,
    float* __restrict__ h1p, float* __restrict__ h2)
{
  int z = blockIdx.z;
  int t = threadIdx.x;
  __shared__ __align__(16) float As[32][33];
  __shared__ __align__(16) float Bs[32][64];

  if (z == 32) {
    // W2 swizzle: 16 blocks (y*4+x), each covers 4 ks values for one r.
    int sub = blockIdx.y * 4 + blockIdx.x;   // 0..15
    int r = sub >> 2, ks0 = (sub & 3) * 4;
    int ct = t >> 6, l = t & 63;
    #pragma unroll
    for (int ko = 0; ko < 4; ++ko) {
      int ks = ks0 + ko;
      ushort us[8];
      #pragma unroll
      for (int j = 0; j < 8; ++j) {
        int d = ks * 16 + ((j >> 2) * 8) + ((l >> 5) * 4) + (j & 3);
        int e = ct * 32 + (l & 31);
        us[j] = f2b(W2[(r * 256 + d) * 128 + e]);
      }
      uint4 pk;
      pk.x = (uint)us[0] | ((uint)us[1] << 16);
      pk.y = (uint)us[2] | ((uint)us[3] << 16);
      pk.z = (uint)us[4] | ((uint)us[5] << 16);
      pk.w = (uint)us[6] | ((uint)us[7] << 16);
      *(uint4*)&W2swz[(((r * 16 + ks) * 4 + ct) * 64 + l) * 8] = pk;
    }
    return;
  }

  int half = z >> 4, b = (z >> 2) & 3, r = z & 3;
  int rt = blockIdx.y, ct = blockIdx.x;
  int tm2 = t >> 4, tn4 = t & 15;
  int arow = t >> 3, akq = (t & 7) * 4;
  int bk = t >> 4, bn4 = (t & 15) * 4;

  const float* A = (half ? f2 : f1) + (size_t)b * 128 * 256;
  const float* W = W1 + (size_t)(r * 512 + half * 256) * 256;
  const float* Ab = A + (rt * 32 + arow) * 256;
  const float* Wb = W + ct * 64 + bn4;

  float4 pa = *(const float4*)&Ab[akq];
  float4 pb0 = *(const float4*)&Wb[bk * 256];
  float4 pb1 = *(const float4*)&Wb[(bk + 16) * 256];

  float acc[2][4];
  #pragma unroll
  for (int i = 0; i < 2; ++i)
    #pragma unroll
    for (int j = 0; j < 4; ++j) acc[i][j] = 0.f;

  for (int kc = 0; kc < 256; kc += 32) {
    __syncthreads();
    As[akq + 0][arow] = pa.x;
    As[akq + 1][arow] = pa.y;
    As[akq + 2][arow] = pa.z;
    As[akq + 3][arow] = pa.w;
    *(float4*)&Bs[bk][bn4] = pb0;
    *(float4*)&Bs[bk + 16][bn4] = pb1;
    __syncthreads();
    if (kc + 32 < 256) {
      pa  = *(const float4*)&Ab[kc + 32 + akq];
      pb0 = *(const float4*)&Wb[(kc + 32 + bk) * 256];
      pb1 = *(const float4*)&Wb[(kc + 32 + bk + 16) * 256];
    }
    #pragma unroll
    for (int kk = 0; kk < 32; ++kk) {
      float2 a = *(const float2*)&As[kk][tm2 * 2];
      float4 w = *(const float4*)&Bs[kk][tn4 * 4];
      acc[0][0] = fmaf(a.x, w.x, acc[0][0]); acc[0][1] = fmaf(a.x, w.y, acc[0][1]);
      acc[0][2] = fmaf(a.x, w.z, acc[0][2]); acc[0][3] = fmaf(a.x, w.w, acc[0][3]);
      acc[1][0] = fmaf(a.y, w.x, acc[1][0]); acc[1][1] = fmaf(a.y, w.y, acc[1][1]);
      acc[1][2] = fmaf(a.y, w.z, acc[1][2]); acc[1][3] = fmaf(a.y, w.w, acc[1][3]);
    }
  }

  int col = ct * 64 + tn4 * 4;
  float4 bv;
  if (half) { bv.x = bv.y = bv.z = bv.w = 0.f; }
  else      { bv = *(const float4*)&b1[r * 256 + col]; }
  float* ho = half ? h2 : h1p;
  #pragma unroll
  for (int qm = 0; qm < 2; ++qm) {
    int row = rt * 32 + tm2 * 2 + qm;
    float4 ov = make_float4(acc[qm][0] + bv.x, acc[qm][1] + bv.y,
                            acc[qm][2] + bv.z, acc[qm][3] + bv.w);
    *(float4*)&ho[((size_t)(b * 4 + r) * 128 + row) * 256 + col] = ov;
  }
}

// ---------------- MFMA scores kernel: register A-fragments, no k-loop barriers ----------------
__global__ __launch_bounds__(256, 2) void k_scores_mfma(
    const float* __restrict__ h1p, const float* __restrict__ h2,
    const ushort* __restrict__ W2swz, const float* __restrict__ b2,
    const float* __restrict__ w3, const float* __restrict__ b3,
    float* __restrict__ scores)
{
  int bid = blockIdx.x;        // 1024 blocks: b(4) x r(4) x it(8) x jt(8)
  int jt = bid & 7;
  int it = (bid >> 3) & 7;
  int r  = (bid >> 6) & 3;
  int b  = bid >> 8;
  int t = threadIdx.x, w = t >> 6, l = t & 63;
  __shared__ float h1s[16][RS];
  __shared__ float h2s[16][RS];

  const float* h1g = h1p + ((b * 4 + r) * 128 + it * 16) * 256;
  const float* h2g = h2  + ((b * 4 + r) * 128 + jt * 16) * 256;
  for (int idx = t; idx < 1024; idx += 256) {
    int ii = idx >> 6, d4 = (idx & 63) << 2;
    *(float4*)&h1s[ii][d4] = *(const float4*)&h1g[ii * 256 + d4];
    *(float4*)&h2s[ii][d4] = *(const float4*)&h2g[ii * 256 + d4];
  }

  f32x16 acc[2][4];
  #pragma unroll
  for (int q = 0; q < 2; ++q)
    #pragma unroll
    for (int c = 0; c < 4; ++c)
      #pragma unroll
      for (int e = 0; e < 16; ++e) acc[q][c][e] = 0.f;

  const ushort* bptr = W2swz + r * (16 * 4 * 64 * 8);
  int kb_lane = (l >> 5) << 2;   // 0 or 4
  int m31 = l & 31;
  int jrow = l & 15;
  int irow0 = m31 >> 4;          // 0 or 1 within each 32-row tile

  __syncthreads();   // h1s/h2s staged

  #pragma unroll 2
  for (int ks = 0; ks < 16; ++ks) {
    // Each lane's A-fragment for mfma_32x32x16_bf16 is exactly the 8 values it
    // computes here: row = rt*32 + (l&31), k = ks*16 + (l>>5)*4 + (j&3) + (j>>2)*8.
    bf16x8 af0, af1;
    #pragma unroll
    for (int q = 0; q < 2; ++q) {
      int rt = w * 2 + q;
      int irow = rt * 2 + irow0;
      int kb0 = ks * 16 + kb_lane;
      float4 xa = *(const float4*)&h1s[irow][kb0];
      float4 xb = *(const float4*)&h1s[irow][kb0 + 8];
      float4 ya = *(const float4*)&h2s[jrow][kb0];
      float4 yb = *(const float4*)&h2s[jrow][kb0 + 8];
      float v0 = fmaxf(xa.x + ya.x, 0.f), v1 = fmaxf(xa.y + ya.y, 0.f);
      float v2 = fmaxf(xa.z + ya.z, 0.f), v3 = fmaxf(xa.w + ya.w, 0.f);
      float v4 = fmaxf(xb.x + yb.x, 0.f), v5 = fmaxf(xb.y + yb.y, 0.f);
      float v6 = fmaxf(xb.z + yb.z, 0.f), v7 = fmaxf(xb.w + yb.w, 0.f);
      uint4 pk;
      pk.x = (uint)f2b(v0) | ((uint)f2b(v1) << 16);
      pk.y = (uint)f2b(v2) | ((uint)f2b(v3) << 16);
      pk.z = (uint)f2b(v4) | ((uint)f2b(v5) << 16);
      pk.w = (uint)f2b(v6) | ((uint)f2b(v7) << 16);
      if (q == 0) af0 = __builtin_bit_cast(bf16x8, pk);
      else        af1 = __builtin_bit_cast(bf16x8, pk);
    }
    #pragma unroll
    for (int ct = 0; ct < 4; ++ct) {
      uint4 braw = *(const uint4*)&bptr[((ks * 4 + ct) * 64 + l) * 8];
      bf16x8 bfr = __builtin_bit_cast(bf16x8, braw);
      acc[0][ct] = __builtin_amdgcn_mfma_f32_32x32x16_bf16(af0, bfr, acc[0][ct], 0, 0, 0);
      acc[1][ct] = __builtin_amdgcn_mfma_f32_32x32x16_bf16(af1, bfr, acc[1][ct], 0, 0, 0);
    }
  }

  // ---- epilogue: s[p] = sum_e w3[e]*relu(g[p][e]+b2[e]) + b3 ----
  float b3v = b3[r];
  float* sc_base = scores + (((b * 4 + r) * 128 + it * 16) * 128) + jt * 16;
  #pragma unroll
  for (int q = 0; q < 2; ++q) {
    float sp[16];
    #pragma unroll
    for (int g = 0; g < 16; ++g) sp[g] = 0.f;
    #pragma unroll
    for (int ct = 0; ct < 4; ++ct) {
      int e = ct * 32 + m31;
      float w3v = w3[r * 128 + e];
      float b2v = b2[r * 128 + e];
      #pragma unroll
      for (int g = 0; g < 16; ++g)
        sp[g] = fmaf(w3v, fmaxf(acc[q][ct][g] + b2v, 0.f), sp[g]);
    }
    #pragma unroll
    for (int off = 16; off >= 1; off >>= 1)
      #pragma unroll
      for (int g = 0; g < 16; ++g)
        sp[g] += __shfl_xor(sp[g], off, 64);
    if (m31 == 0) {
      int half4 = (l >> 5) << 2;
      #pragma unroll
      for (int g = 0; g < 16; ++g) {
        int p = (w * 2 + q) * 32 + (g & 3) + 8 * (g >> 2) + half4;
        sc_base[(p >> 4) * 128 + (p & 15)] = sp[g] + b3v;
      }
    }
  }
}

__global__ __launch_bounds__(128) void k_softmax_rel(
    const float* __restrict__ scores, const float* __restrict__ f2,
    float* __restrict__ all_rel)
{
  int bid = blockIdx.x;        // 2048 blocks: b(4) x r(4) x i(128)
  int i = bid & 127;
  int r = (bid >> 7) & 3;
  int b = bid >> 9;
  int t = threadIdx.x;
  __shared__ float sraw[128];
  __shared__ float p[128];
  float s = scores[((b * 4 + r) * 128 + i) * 128 + t];
  sraw[t] = s;
  __syncthreads();
  float m = -1e30f;
  for (int j = 0; j < 128; ++j) m = fmaxf(m, sraw[j]);
  float pv = expf(s - m);
  p[t] = pv;
  __syncthreads();
  float sum = 0.f;
  for (int j = 0; j < 128; ++j) sum += p[j];
  float inv = 1.f / sum;
  for (int d = t; d < 256; d += 128) {
    float a = 0.f;
    for (int j = 0; j < 128; ++j)
      a = fmaf(p[j], f2[(b * 128 + j) * 256 + d], a);
    all_rel[(b * 128 + i) * 1024 + r * 256 + d] = a * inv;
  }
}

extern "C" void kernel_launch(void* const* d_in, const int* in_sizes, int n_in,
                              void* d_out, int out_size, void* d_ws, size_t ws_size,
                              hipStream_t stream) {
  const float* f1  = (const float*)d_in[0];
  const float* f2  = (const float*)d_in[1];
  const float* W1  = (const float*)d_in[2];
  const float* b1  = (const float*)d_in[3];
  const float* W2  = (const float*)d_in[4];
  const float* b2  = (const float*)d_in[5];
  const float* w3  = (const float*)d_in[6];
  const float* b3  = (const float*)d_in[7];
  const float* Wa1 = (const float*)d_in[8];
  const float* ba1 = (const float*)d_in[9];
  const float* Wa2 = (const float*)d_in[10];
  const float* ba2 = (const float*)d_in[11];
  float* out = (float*)d_out;
  float* ws = (float*)d_ws;

  float* h1p     = ws;                 // 524288 floats (2MB)
  float* h2      = ws + 524288;        // 524288
  float* scores  = ws + 1048576;       // 262144 (1MB)
  float* all_rel = ws + 1310720;       // 524288 (2MB)
  float* hidden  = ws + 1835008;       // 262144 (1MB); W2swz aliases here (dead by then)
  ushort* W2swz  = (ushort*)(ws + 1835008);
  // Split-K partials alias dead regions (stream-ordered):
  float* p1 = ws;                      // 4x 512x512 floats = h1p+h2 (dead after scores)
  float* p2 = ws + 1310720;            // 4x 512x256 floats = all_rel (dead after gemm1)

  hipLaunchKernelGGL(k_proj_w2, dim3(4, 4, 33), dim3(256), 0, stream,
                     f1, f2, W1, b1, W2, W2swz, h1p, h2);
  hipLaunchKernelGGL(k_scores_mfma, dim3(1024), dim3(256), 0, stream,
                     h1p, h2, W2swz, b2, w3, b3, scores);
  hipLaunchKernelGGL(k_softmax_rel, dim3(2048), dim3(128), 0, stream,
                     scores, f2, all_rel);
  // gemm1: hidden = relu(all_rel[512,1024] @ Wa1[1024,512] + ba1)
  hipLaunchKernelGGL((gemm_part<256>), dim3(8, 16, 4), dim3(256), 0, stream,
                     all_rel, Wa1, p1, 1024, 512, 512);
  hipLaunchKernelGGL((reduce_bias_act<4>), dim3(256), dim3(256), 0, stream,
                     p1, ba1, hidden, 512 * 512, 512, 1);
  // gemm2: out = hidden[512,512] @ Wa2[512,256] + ba2
  hipLaunchKernelGGL((gemm_part<128>), dim3(4, 16, 4), dim3(256), 0, stream,
                     hidden, Wa2, p2, 512, 256, 512);
  hipLaunchKernelGGL((reduce_bias_act<4>), dim3(128), dim3(256), 0, stream,
                     p2, ba2, out, 512 * 256, 256, 0);
}

// Round 6
// 86.083 us; speedup vs baseline: 1.1797x; 1.1797x over previous
//
#include <hip/hip_runtime.h>

// Shapes: B=4, N1=N2=128, D=256, R=4, E=D/2=128
// Pipeline:
//   A: h1p/h2 projections + W2 pre-swizzle  [one kernel, fp32 32x64 tiles]
//   B: scores via bf16 MFMA — wave owns 32 pairs x N=128, acc=64 AGPR, 4 waves/SIMD
//   C: softmax + rel
//   D: final MLP  [fp32 32x64-tile GEMM, split-K x4 + reduce]

typedef __bf16 bf16x8 __attribute__((ext_vector_type(8)));
typedef float f32x16 __attribute__((ext_vector_type(16)));

#define RS 268

static __device__ __forceinline__ ushort f2b(float f) {
  __bf16 h = (__bf16)f;
  return __builtin_bit_cast(ushort, h);
}

// ---------------- fp32 32x64-tile GEMM core (micro 2x4, KC=32) ----------------
template<int KBLK>
static __device__ __forceinline__ void gemm32x64_body(
    const float* __restrict__ A, const float* __restrict__ W,
    float* __restrict__ Cout, int K, int N, int rt, int ct, int k0)
{
  int t = threadIdx.x;
  int tm2 = t >> 4;
  int tn4 = t & 15;
  int arow = t >> 3;
  int akq = (t & 7) * 4;
  int bk = t >> 4;
  int bn4 = (t & 15) * 4;
  __shared__ __align__(16) float As[32][33];
  __shared__ __align__(16) float Bs[32][64];

  const float* Ab = A + (size_t)(rt * 32 + arow) * K + k0;
  const float* Wb = W + (size_t)k0 * N + ct * 64 + bn4;

  float4 pa = *(const float4*)&Ab[akq];
  float4 pb0 = *(const float4*)&Wb[(size_t)bk * N];
  float4 pb1 = *(const float4*)&Wb[(size_t)(bk + 16) * N];

  float acc[2][4];
  #pragma unroll
  for (int i = 0; i < 2; ++i)
    #pragma unroll
    for (int j = 0; j < 4; ++j) acc[i][j] = 0.f;

  for (int kc = 0; kc < KBLK; kc += 32) {
    __syncthreads();
    As[akq + 0][arow] = pa.x;
    As[akq + 1][arow] = pa.y;
    As[akq + 2][arow] = pa.z;
    As[akq + 3][arow] = pa.w;
    *(float4*)&Bs[bk][bn4] = pb0;
    *(float4*)&Bs[bk + 16][bn4] = pb1;
    __syncthreads();
    if (kc + 32 < KBLK) {
      pa  = *(const float4*)&Ab[kc + 32 + akq];
      pb0 = *(const float4*)&Wb[(size_t)(kc + 32 + bk) * N];
      pb1 = *(const float4*)&Wb[(size_t)(kc + 32 + bk + 16) * N];
    }
    #pragma unroll
    for (int kk = 0; kk < 32; ++kk) {
      float2 a = *(const float2*)&As[kk][tm2 * 2];
      float4 w = *(const float4*)&Bs[kk][tn4 * 4];
      acc[0][0] = fmaf(a.x, w.x, acc[0][0]); acc[0][1] = fmaf(a.x, w.y, acc[0][1]);
      acc[0][2] = fmaf(a.x, w.z, acc[0][2]); acc[0][3] = fmaf(a.x, w.w, acc[0][3]);
      acc[1][0] = fmaf(a.y, w.x, acc[1][0]); acc[1][1] = fmaf(a.y, w.y, acc[1][1]);
      acc[1][2] = fmaf(a.y, w.z, acc[1][2]); acc[1][3] = fmaf(a.y, w.w, acc[1][3]);
    }
  }

  int col = ct * 64 + tn4 * 4;
  #pragma unroll
  for (int qm = 0; qm < 2; ++qm) {
    int row = rt * 32 + tm2 * 2 + qm;
    float4 ov = make_float4(acc[qm][0], acc[qm][1], acc[qm][2], acc[qm][3]);
    *(float4*)&Cout[(size_t)row * N + col] = ov;
  }
}

template<int KBLK>
__global__ __launch_bounds__(256) void gemm_part(
    const float* __restrict__ A, const float* __restrict__ W,
    float* __restrict__ part, int K, int N, int M)
{
  int kp = blockIdx.z;
  gemm32x64_body<KBLK>(A, W, part + (size_t)kp * M * N, K, N,
                       blockIdx.y, blockIdx.x, kp * KBLK);
}

template<int P>
__global__ __launch_bounds__(256) void reduce_bias_act(
    const float* __restrict__ part, const float* __restrict__ bias,
    float* __restrict__ C, int MN, int N, int act)
{
  int idx4 = (blockIdx.x * 256 + threadIdx.x) * 4;
  if (idx4 >= MN) return;
  float4 s = *(const float4*)&part[idx4];
  #pragma unroll
  for (int p = 1; p < P; ++p) {
    float4 v = *(const float4*)&part[(size_t)p * MN + idx4];
    s.x += v.x; s.y += v.y; s.z += v.z; s.w += v.w;
  }
  float4 bv = *(const float4*)&bias[idx4 & (N - 1)];
  s.x += bv.x; s.y += bv.y; s.z += bv.z; s.w += bv.w;
  if (act) {
    s.x = fmaxf(s.x, 0.f); s.y = fmaxf(s.y, 0.f);
    s.z = fmaxf(s.z, 0.f); s.w = fmaxf(s.w, 0.f);
  }
  *(float4*)&C[idx4] = s;
}

// ---------------- projection (z<32) + W2 pre-swizzle (z==32) ----------------
__global__ __launch_bounds__(256) void k_proj_w2(
    const float* __restrict__ f1, const float* __restrict__ f2,
    const float* __restrict__ W1, const float* __restrict__ b1,
    const float* __restrict__ W2, ushort* __restrict__ W2swz,
    float* __restrict__ h1p, float* __restrict__ h2)
{
  int z = blockIdx.z;
  int t = threadIdx.x;
  __shared__ __align__(16) float As[32][33];
  __shared__ __align__(16) float Bs[32][64];

  if (z == 32) {
    int sub = blockIdx.y * 4 + blockIdx.x;   // 0..15
    int r = sub >> 2, ks0 = (sub & 3) * 4;
    int ct = t >> 6, l = t & 63;
    #pragma unroll
    for (int ko = 0; ko < 4; ++ko) {
      int ks = ks0 + ko;
      ushort us[8];
      #pragma unroll
      for (int j = 0; j < 8; ++j) {
        int d = ks * 16 + ((j >> 2) * 8) + ((l >> 5) * 4) + (j & 3);
        int e = ct * 32 + (l & 31);
        us[j] = f2b(W2[(r * 256 + d) * 128 + e]);
      }
      uint4 pk;
      pk.x = (uint)us[0] | ((uint)us[1] << 16);
      pk.y = (uint)us[2] | ((uint)us[3] << 16);
      pk.z = (uint)us[4] | ((uint)us[5] << 16);
      pk.w = (uint)us[6] | ((uint)us[7] << 16);
      *(uint4*)&W2swz[(((r * 16 + ks) * 4 + ct) * 64 + l) * 8] = pk;
    }
    return;
  }

  int half = z >> 4, b = (z >> 2) & 3, r = z & 3;
  int rt = blockIdx.y, ct = blockIdx.x;
  int tm2 = t >> 4, tn4 = t & 15;
  int arow = t >> 3, akq = (t & 7) * 4;
  int bk = t >> 4, bn4 = (t & 15) * 4;

  const float* A = (half ? f2 : f1) + (size_t)b * 128 * 256;
  const float* W = W1 + (size_t)(r * 512 + half * 256) * 256;
  const float* Ab = A + (rt * 32 + arow) * 256;
  const float* Wb = W + ct * 64 + bn4;

  float4 pa = *(const float4*)&Ab[akq];
  float4 pb0 = *(const float4*)&Wb[bk * 256];
  float4 pb1 = *(const float4*)&Wb[(bk + 16) * 256];

  float acc[2][4];
  #pragma unroll
  for (int i = 0; i < 2; ++i)
    #pragma unroll
    for (int j = 0; j < 4; ++j) acc[i][j] = 0.f;

  for (int kc = 0; kc < 256; kc += 32) {
    __syncthreads();
    As[akq + 0][arow] = pa.x;
    As[akq + 1][arow] = pa.y;
    As[akq + 2][arow] = pa.z;
    As[akq + 3][arow] = pa.w;
    *(float4*)&Bs[bk][bn4] = pb0;
    *(float4*)&Bs[bk + 16][bn4] = pb1;
    __syncthreads();
    if (kc + 32 < 256) {
      pa  = *(const float4*)&Ab[kc + 32 + akq];
      pb0 = *(const float4*)&Wb[(kc + 32 + bk) * 256];
      pb1 = *(const float4*)&Wb[(kc + 32 + bk + 16) * 256];
    }
    #pragma unroll
    for (int kk = 0; kk < 32; ++kk) {
      float2 a = *(const float2*)&As[kk][tm2 * 2];
      float4 w = *(const float4*)&Bs[kk][tn4 * 4];
      acc[0][0] = fmaf(a.x, w.x, acc[0][0]); acc[0][1] = fmaf(a.x, w.y, acc[0][1]);
      acc[0][2] = fmaf(a.x, w.z, acc[0][2]); acc[0][3] = fmaf(a.x, w.w, acc[0][3]);
      acc[1][0] = fmaf(a.y, w.x, acc[1][0]); acc[1][1] = fmaf(a.y, w.y, acc[1][1]);
      acc[1][2] = fmaf(a.y, w.z, acc[1][2]); acc[1][3] = fmaf(a.y, w.w, acc[1][3]);
    }
  }

  int col = ct * 64 + tn4 * 4;
  float4 bv;
  if (half) { bv.x = bv.y = bv.z = bv.w = 0.f; }
  else      { bv = *(const float4*)&b1[r * 256 + col]; }
  float* ho = half ? h2 : h1p;
  #pragma unroll
  for (int qm = 0; qm < 2; ++qm) {
    int row = rt * 32 + tm2 * 2 + qm;
    float4 ov = make_float4(acc[qm][0] + bv.x, acc[qm][1] + bv.y,
                            acc[qm][2] + bv.z, acc[qm][3] + bv.w);
    *(float4*)&ho[((size_t)(b * 4 + r) * 128 + row) * 256 + col] = ov;
  }
}

// ---------------- MFMA scores kernel: 1 row-tile/wave, 64 AGPR acc, 4 waves/SIMD ----------------
// Block = 8 i-rows x 16 j-rows = 128 pairs; wave w owns pairs [w*32, w*32+32).
__global__ __launch_bounds__(256, 4) void k_scores_mfma(
    const float* __restrict__ h1p, const float* __restrict__ h2,
    const ushort* __restrict__ W2swz, const float* __restrict__ b2,
    const float* __restrict__ w3, const float* __restrict__ b3,
    float* __restrict__ scores)
{
  int bid = blockIdx.x;        // 2048 blocks: b(4) x r(4) x it(16) x jt(8)
  int jt = bid & 7;
  int it = (bid >> 3) & 15;
  int r  = (bid >> 7) & 3;
  int b  = bid >> 9;
  int t = threadIdx.x, w = t >> 6, l = t & 63;
  __shared__ float h1s[8][RS];
  __shared__ float h2s[16][RS];

  const float* h1g = h1p + ((b * 4 + r) * 128 + it * 8) * 256;
  const float* h2g = h2  + ((b * 4 + r) * 128 + jt * 16) * 256;
  for (int idx = t; idx < 512; idx += 256) {
    int ii = idx >> 6, d4 = (idx & 63) << 2;
    *(float4*)&h1s[ii][d4] = *(const float4*)&h1g[ii * 256 + d4];
  }
  for (int idx = t; idx < 1024; idx += 256) {
    int ii = idx >> 6, d4 = (idx & 63) << 2;
    *(float4*)&h2s[ii][d4] = *(const float4*)&h2g[ii * 256 + d4];
  }

  f32x16 acc[4];
  #pragma unroll
  for (int c = 0; c < 4; ++c)
    #pragma unroll
    for (int e = 0; e < 16; ++e) acc[c][e] = 0.f;

  const ushort* bptr = W2swz + r * (16 * 4 * 64 * 8);
  int kb_lane = (l >> 5) << 2;     // 0 or 4
  int m31 = l & 31;                // pair-in-wave = A-row within 32-tile
  int jrow = m31 & 15;             // j index
  int irow = w * 2 + (m31 >> 4);   // i index (0..7)

  __syncthreads();   // h1s/h2s staged

  for (int ks = 0; ks < 16; ++ks) {
    // A-fragment: row = l&31, k = ks*16 + (l>>5)*4 + (j&3) + (j>>2)*8
    int kb0 = ks * 16 + kb_lane;
    float4 xa = *(const float4*)&h1s[irow][kb0];
    float4 xb = *(const float4*)&h1s[irow][kb0 + 8];
    float4 ya = *(const float4*)&h2s[jrow][kb0];
    float4 yb = *(const float4*)&h2s[jrow][kb0 + 8];
    float v0 = fmaxf(xa.x + ya.x, 0.f), v1 = fmaxf(xa.y + ya.y, 0.f);
    float v2 = fmaxf(xa.z + ya.z, 0.f), v3 = fmaxf(xa.w + ya.w, 0.f);
    float v4 = fmaxf(xb.x + yb.x, 0.f), v5 = fmaxf(xb.y + yb.y, 0.f);
    float v6 = fmaxf(xb.z + yb.z, 0.f), v7 = fmaxf(xb.w + yb.w, 0.f);
    uint4 pk;
    pk.x = (uint)f2b(v0) | ((uint)f2b(v1) << 16);
    pk.y = (uint)f2b(v2) | ((uint)f2b(v3) << 16);
    pk.z = (uint)f2b(v4) | ((uint)f2b(v5) << 16);
    pk.w = (uint)f2b(v6) | ((uint)f2b(v7) << 16);
    bf16x8 af = __builtin_bit_cast(bf16x8, pk);
    #pragma unroll
    for (int ct = 0; ct < 4; ++ct) {
      uint4 braw = *(const uint4*)&bptr[((ks * 4 + ct) * 64 + l) * 8];
      bf16x8 bfr = __builtin_bit_cast(bf16x8, braw);
      acc[ct] = __builtin_amdgcn_mfma_f32_32x32x16_bf16(af, bfr, acc[ct], 0, 0, 0);
    }
  }

  // ---- epilogue: s[p] = sum_e w3[e]*relu(g[p][e]+b2[e]) + b3 ----
  // C/D layout (32x32): col e = ct*32 + (l&31), row = (g&3) + 8*(g>>2) + 4*(l>>5)
  float b3v = b3[r];
  float* sc_base = scores + (((b * 4 + r) * 128 + it * 8) * 128) + jt * 16;
  float sp[16];
  #pragma unroll
  for (int g = 0; g < 16; ++g) sp[g] = 0.f;
  #pragma unroll
  for (int ct = 0; ct < 4; ++ct) {
    int e = ct * 32 + m31;
    float w3v = w3[r * 128 + e];
    float b2v = b2[r * 128 + e];
    #pragma unroll
    for (int g = 0; g < 16; ++g)
      sp[g] = fmaf(w3v, fmaxf(acc[ct][g] + b2v, 0.f), sp[g]);
  }
  #pragma unroll
  for (int off = 16; off >= 1; off >>= 1)
    #pragma unroll
    for (int g = 0; g < 16; ++g)
      sp[g] += __shfl_xor(sp[g], off, 64);
  if (m31 == 0) {
    int half4 = (l >> 5) << 2;
    #pragma unroll
    for (int g = 0; g < 16; ++g) {
      int p = w * 32 + (g & 3) + 8 * (g >> 2) + half4;   // pair in [0,128)
      sc_base[(p >> 4) * 128 + (p & 15)] = sp[g] + b3v;
    }
  }
}

__global__ __launch_bounds__(128) void k_softmax_rel(
    const float* __restrict__ scores, const float* __restrict__ f2,
    float* __restrict__ all_rel)
{
  int bid = blockIdx.x;        // 2048 blocks: b(4) x r(4) x i(128)
  int i = bid & 127;
  int r = (bid >> 7) & 3;
  int b = bid >> 9;
  int t = threadIdx.x;
  __shared__ float sraw[128];
  __shared__ float p[128];
  float s = scores[((b * 4 + r) * 128 + i) * 128 + t];
  sraw[t] = s;
  __syncthreads();
  float m = -1e30f;
  for (int j = 0; j < 128; ++j) m = fmaxf(m, sraw[j]);
  float pv = expf(s - m);
  p[t] = pv;
  __syncthreads();
  float sum = 0.f;
  for (int j = 0; j < 128; ++j) sum += p[j];
  float inv = 1.f / sum;
  for (int d = t; d < 256; d += 128) {
    float a = 0.f;
    for (int j = 0; j < 128; ++j)
      a = fmaf(p[j], f2[(b * 128 + j) * 256 + d], a);
    all_rel[(b * 128 + i) * 1024 + r * 256 + d] = a * inv;
  }
}

extern "C" void kernel_launch(void* const* d_in, const int* in_sizes, int n_in,
                              void* d_out, int out_size, void* d_ws, size_t ws_size,
                              hipStream_t stream) {
  const float* f1  = (const float*)d_in[0];
  const float* f2  = (const float*)d_in[1];
  const float* W1  = (const float*)d_in[2];
  const float* b1  = (const float*)d_in[3];
  const float* W2  = (const float*)d_in[4];
  const float* b2  = (const float*)d_in[5];
  const float* w3  = (const float*)d_in[6];
  const float* b3  = (const float*)d_in[7];
  const float* Wa1 = (const float*)d_in[8];
  const float* ba1 = (const float*)d_in[9];
  const float* Wa2 = (const float*)d_in[10];
  const float* ba2 = (const float*)d_in[11];
  float* out = (float*)d_out;
  float* ws = (float*)d_ws;

  float* h1p     = ws;                 // 524288 floats (2MB)
  float* h2      = ws + 524288;        // 524288
  float* scores  = ws + 1048576;       // 262144 (1MB)
  float* all_rel = ws + 1310720;       // 524288 (2MB)
  float* hidden  = ws + 1835008;       // 262144 (1MB); W2swz aliases here (dead by then)
  ushort* W2swz  = (ushort*)(ws + 1835008);
  float* p1 = ws;                      // 4x 512x512 floats = h1p+h2 (dead after scores)
  float* p2 = ws + 1310720;            // 4x 512x256 floats = all_rel (dead after gemm1)

  hipLaunchKernelGGL(k_proj_w2, dim3(4, 4, 33), dim3(256), 0, stream,
                     f1, f2, W1, b1, W2, W2swz, h1p, h2);
  hipLaunchKernelGGL(k_scores_mfma, dim3(2048), dim3(256), 0, stream,
                     h1p, h2, W2swz, b2, w3, b3, scores);
  hipLaunchKernelGGL(k_softmax_rel, dim3(2048), dim3(128), 0, stream,
                     scores, f2, all_rel);
  hipLaunchKernelGGL((gemm_part<256>), dim3(8, 16, 4), dim3(256), 0, stream,
                     all_rel, Wa1, p1, 1024, 512, 512);
  hipLaunchKernelGGL((reduce_bias_act<4>), dim3(256), dim3(256), 0, stream,
                     p1, ba1, hidden, 512 * 512, 512, 1);
  hipLaunchKernelGGL((gemm_part<128>), dim3(4, 16, 4), dim3(256), 0, stream,
                     hidden, Wa2, p2, 512, 256, 512);
  hipLaunchKernelGGL((reduce_bias_act<4>), dim3(128), dim3(256), 0, stream,
                     p2, ba2, out, 512 * 256, 256, 0);
}

// Round 7
// 82.192 us; speedup vs baseline: 1.2356x; 1.0473x over previous
//
#include <hip/hip_runtime.h>

// Shapes: B=4, N1=N2=128, D=256, R=4, E=D/2=128
// Pipeline:
//   A: h1p/h2 projections + W2/f2 fp16 pre-swizzle  [one kernel]
//   B: scores via fp16 MFMA (reg A-fragments, 4 waves/SIMD)
//   C: softmax+rel via fp16 MFMA (P rows lane-resident, no LDS)
//   D: final MLP  [fp32 32x64-tile GEMM, split-K x4 + reduce]

typedef _Float16 f16x8 __attribute__((ext_vector_type(8)));
typedef float f32x16 __attribute__((ext_vector_type(16)));

#define RS 268

static __device__ __forceinline__ ushort f2h(float f) {
  _Float16 h = (_Float16)f;
  return __builtin_bit_cast(ushort, h);
}

// ---------------- fp32 32x64-tile GEMM core (micro 2x4, KC=32) ----------------
template<int KBLK>
static __device__ __forceinline__ void gemm32x64_body(
    const float* __restrict__ A, const float* __restrict__ W,
    float* __restrict__ Cout, int K, int N, int rt, int ct, int k0)
{
  int t = threadIdx.x;
  int tm2 = t >> 4;
  int tn4 = t & 15;
  int arow = t >> 3;
  int akq = (t & 7) * 4;
  int bk = t >> 4;
  int bn4 = (t & 15) * 4;
  __shared__ __align__(16) float As[32][33];
  __shared__ __align__(16) float Bs[32][64];

  const float* Ab = A + (size_t)(rt * 32 + arow) * K + k0;
  const float* Wb = W + (size_t)k0 * N + ct * 64 + bn4;

  float4 pa = *(const float4*)&Ab[akq];
  float4 pb0 = *(const float4*)&Wb[(size_t)bk * N];
  float4 pb1 = *(const float4*)&Wb[(size_t)(bk + 16) * N];

  float acc[2][4];
  #pragma unroll
  for (int i = 0; i < 2; ++i)
    #pragma unroll
    for (int j = 0; j < 4; ++j) acc[i][j] = 0.f;

  for (int kc = 0; kc < KBLK; kc += 32) {
    __syncthreads();
    As[akq + 0][arow] = pa.x;
    As[akq + 1][arow] = pa.y;
    As[akq + 2][arow] = pa.z;
    As[akq + 3][arow] = pa.w;
    *(float4*)&Bs[bk][bn4] = pb0;
    *(float4*)&Bs[bk + 16][bn4] = pb1;
    __syncthreads();
    if (kc + 32 < KBLK) {
      pa  = *(const float4*)&Ab[kc + 32 + akq];
      pb0 = *(const float4*)&Wb[(size_t)(kc + 32 + bk) * N];
      pb1 = *(const float4*)&Wb[(size_t)(kc + 32 + bk + 16) * N];
    }
    #pragma unroll
    for (int kk = 0; kk < 32; ++kk) {
      float2 a = *(const float2*)&As[kk][tm2 * 2];
      float4 w = *(const float4*)&Bs[kk][tn4 * 4];
      acc[0][0] = fmaf(a.x, w.x, acc[0][0]); acc[0][1] = fmaf(a.x, w.y, acc[0][1]);
      acc[0][2] = fmaf(a.x, w.z, acc[0][2]); acc[0][3] = fmaf(a.x, w.w, acc[0][3]);
      acc[1][0] = fmaf(a.y, w.x, acc[1][0]); acc[1][1] = fmaf(a.y, w.y, acc[1][1]);
      acc[1][2] = fmaf(a.y, w.z, acc[1][2]); acc[1][3] = fmaf(a.y, w.w, acc[1][3]);
    }
  }

  int col = ct * 64 + tn4 * 4;
  #pragma unroll
  for (int qm = 0; qm < 2; ++qm) {
    int row = rt * 32 + tm2 * 2 + qm;
    float4 ov = make_float4(acc[qm][0], acc[qm][1], acc[qm][2], acc[qm][3]);
    *(float4*)&Cout[(size_t)row * N + col] = ov;
  }
}

template<int KBLK>
__global__ __launch_bounds__(256) void gemm_part(
    const float* __restrict__ A, const float* __restrict__ W,
    float* __restrict__ part, int K, int N, int M)
{
  int kp = blockIdx.z;
  gemm32x64_body<KBLK>(A, W, part + (size_t)kp * M * N, K, N,
                       blockIdx.y, blockIdx.x, kp * KBLK);
}

template<int P>
__global__ __launch_bounds__(256) void reduce_bias_act(
    const float* __restrict__ part, const float* __restrict__ bias,
    float* __restrict__ C, int MN, int N, int act)
{
  int idx4 = (blockIdx.x * 256 + threadIdx.x) * 4;
  if (idx4 >= MN) return;
  float4 s = *(const float4*)&part[idx4];
  #pragma unroll
  for (int p = 1; p < P; ++p) {
    float4 v = *(const float4*)&part[(size_t)p * MN + idx4];
    s.x += v.x; s.y += v.y; s.z += v.z; s.w += v.w;
  }
  float4 bv = *(const float4*)&bias[idx4 & (N - 1)];
  s.x += bv.x; s.y += bv.y; s.z += bv.z; s.w += bv.w;
  if (act) {
    s.x = fmaxf(s.x, 0.f); s.y = fmaxf(s.y, 0.f);
    s.z = fmaxf(s.z, 0.f); s.w = fmaxf(s.w, 0.f);
  }
  *(float4*)&C[idx4] = s;
}

// ---------------- projection (z<32) + W2 swizzle (z==32) + f2 swizzle (z==33) ----------------
__global__ __launch_bounds__(256) void k_proj_w2(
    const float* __restrict__ f1, const float* __restrict__ f2,
    const float* __restrict__ W1, const float* __restrict__ b1,
    const float* __restrict__ W2, ushort* __restrict__ W2swz,
    ushort* __restrict__ f2swz,
    float* __restrict__ h1p, float* __restrict__ h2)
{
  int z = blockIdx.z;
  int t = threadIdx.x;
  __shared__ __align__(16) float As[32][33];
  __shared__ __align__(16) float Bs[32][64];

  if (z == 32) {
    // W2 -> f16 B-fragment order: [r][ks16][ct4][lane][j8]
    int sub = blockIdx.y * 4 + blockIdx.x;   // 0..15
    int r = sub >> 2, ks0 = (sub & 3) * 4;
    int ct = t >> 6, l = t & 63;
    #pragma unroll
    for (int ko = 0; ko < 4; ++ko) {
      int ks = ks0 + ko;
      ushort us[8];
      #pragma unroll
      for (int j = 0; j < 8; ++j) {
        int d = ks * 16 + ((j >> 2) * 8) + ((l >> 5) * 4) + (j & 3);
        int e = ct * 32 + (l & 31);
        us[j] = f2h(W2[(r * 256 + d) * 128 + e]);
      }
      uint4 pk;
      pk.x = (uint)us[0] | ((uint)us[1] << 16);
      pk.y = (uint)us[2] | ((uint)us[3] << 16);
      pk.z = (uint)us[4] | ((uint)us[5] << 16);
      pk.w = (uint)us[6] | ((uint)us[7] << 16);
      *(uint4*)&W2swz[(((r * 16 + ks) * 4 + ct) * 64 + l) * 8] = pk;
    }
    return;
  }
  if (z == 33) {
    // f2 -> f16 B-fragment order: [b][ks8][ctg8][lane][j8]  (K=j dim, N=d dim)
    int sub = blockIdx.y * 4 + blockIdx.x;   // 0..15
    int w = t >> 6, l = t & 63;
    #pragma unroll
    for (int ko = 0; ko < 4; ++ko) {
      int u = sub * 16 + w * 4 + ko;         // 0..255
      int b = u >> 6, ks = (u >> 3) & 7, ctg = u & 7;
      ushort us[8];
      #pragma unroll
      for (int j = 0; j < 8; ++j) {
        int k = ks * 16 + ((l >> 5) * 4) + (j & 3) + ((j >> 2) * 8);
        int n = ctg * 32 + (l & 31);
        us[j] = f2h(f2[((size_t)b * 128 + k) * 256 + n]);
      }
      uint4 pk;
      pk.x = (uint)us[0] | ((uint)us[1] << 16);
      pk.y = (uint)us[2] | ((uint)us[3] << 16);
      pk.z = (uint)us[4] | ((uint)us[5] << 16);
      pk.w = (uint)us[6] | ((uint)us[7] << 16);
      *(uint4*)&f2swz[(((b * 8 + ks) * 8 + ctg) * 64 + l) * 8] = pk;
    }
    return;
  }

  int half = z >> 4, b = (z >> 2) & 3, r = z & 3;
  int rt = blockIdx.y, ct = blockIdx.x;
  int tm2 = t >> 4, tn4 = t & 15;
  int arow = t >> 3, akq = (t & 7) * 4;
  int bk = t >> 4, bn4 = (t & 15) * 4;

  const float* A = (half ? f2 : f1) + (size_t)b * 128 * 256;
  const float* W = W1 + (size_t)(r * 512 + half * 256) * 256;
  const float* Ab = A + (rt * 32 + arow) * 256;
  const float* Wb = W + ct * 64 + bn4;

  float4 pa = *(const float4*)&Ab[akq];
  float4 pb0 = *(const float4*)&Wb[bk * 256];
  float4 pb1 = *(const float4*)&Wb[(bk + 16) * 256];

  float acc[2][4];
  #pragma unroll
  for (int i = 0; i < 2; ++i)
    #pragma unroll
    for (int j = 0; j < 4; ++j) acc[i][j] = 0.f;

  for (int kc = 0; kc < 256; kc += 32) {
    __syncthreads();
    As[akq + 0][arow] = pa.x;
    As[akq + 1][arow] = pa.y;
    As[akq + 2][arow] = pa.z;
    As[akq + 3][arow] = pa.w;
    *(float4*)&Bs[bk][bn4] = pb0;
    *(float4*)&Bs[bk + 16][bn4] = pb1;
    __syncthreads();
    if (kc + 32 < 256) {
      pa  = *(const float4*)&Ab[kc + 32 + akq];
      pb0 = *(const float4*)&Wb[(kc + 32 + bk) * 256];
      pb1 = *(const float4*)&Wb[(kc + 32 + bk + 16) * 256];
    }
    #pragma unroll
    for (int kk = 0; kk < 32; ++kk) {
      float2 a = *(const float2*)&As[kk][tm2 * 2];
      float4 w = *(const float4*)&Bs[kk][tn4 * 4];
      acc[0][0] = fmaf(a.x, w.x, acc[0][0]); acc[0][1] = fmaf(a.x, w.y, acc[0][1]);
      acc[0][2] = fmaf(a.x, w.z, acc[0][2]); acc[0][3] = fmaf(a.x, w.w, acc[0][3]);
      acc[1][0] = fmaf(a.y, w.x, acc[1][0]); acc[1][1] = fmaf(a.y, w.y, acc[1][1]);
      acc[1][2] = fmaf(a.y, w.z, acc[1][2]); acc[1][3] = fmaf(a.y, w.w, acc[1][3]);
    }
  }

  int col = ct * 64 + tn4 * 4;
  float4 bv;
  if (half) { bv.x = bv.y = bv.z = bv.w = 0.f; }
  else      { bv = *(const float4*)&b1[r * 256 + col]; }
  float* ho = half ? h2 : h1p;
  #pragma unroll
  for (int qm = 0; qm < 2; ++qm) {
    int row = rt * 32 + tm2 * 2 + qm;
    float4 ov = make_float4(acc[qm][0] + bv.x, acc[qm][1] + bv.y,
                            acc[qm][2] + bv.z, acc[qm][3] + bv.w);
    *(float4*)&ho[((size_t)(b * 4 + r) * 128 + row) * 256 + col] = ov;
  }
}

// ---------------- fp16 MFMA scores kernel: 1 row-tile/wave, 4 waves/SIMD ----------------
__global__ __launch_bounds__(256, 4) void k_scores_mfma(
    const float* __restrict__ h1p, const float* __restrict__ h2,
    const ushort* __restrict__ W2swz, const float* __restrict__ b2,
    const float* __restrict__ w3, const float* __restrict__ b3,
    float* __restrict__ scores)
{
  int bid = blockIdx.x;        // 2048 blocks: b(4) x r(4) x it(16) x jt(8)
  int jt = bid & 7;
  int it = (bid >> 3) & 15;
  int r  = (bid >> 7) & 3;
  int b  = bid >> 9;
  int t = threadIdx.x, w = t >> 6, l = t & 63;
  __shared__ float h1s[8][RS];
  __shared__ float h2s[16][RS];

  const float* h1g = h1p + ((b * 4 + r) * 128 + it * 8) * 256;
  const float* h2g = h2  + ((b * 4 + r) * 128 + jt * 16) * 256;
  for (int idx = t; idx < 512; idx += 256) {
    int ii = idx >> 6, d4 = (idx & 63) << 2;
    *(float4*)&h1s[ii][d4] = *(const float4*)&h1g[ii * 256 + d4];
  }
  for (int idx = t; idx < 1024; idx += 256) {
    int ii = idx >> 6, d4 = (idx & 63) << 2;
    *(float4*)&h2s[ii][d4] = *(const float4*)&h2g[ii * 256 + d4];
  }

  f32x16 acc[4];
  #pragma unroll
  for (int c = 0; c < 4; ++c)
    #pragma unroll
    for (int e = 0; e < 16; ++e) acc[c][e] = 0.f;

  const ushort* bptr = W2swz + r * (16 * 4 * 64 * 8);
  int kb_lane = (l >> 5) << 2;
  int m31 = l & 31;
  int jrow = m31 & 15;
  int irow = w * 2 + (m31 >> 4);

  __syncthreads();

  for (int ks = 0; ks < 16; ++ks) {
    int kb0 = ks * 16 + kb_lane;
    float4 xa = *(const float4*)&h1s[irow][kb0];
    float4 xb = *(const float4*)&h1s[irow][kb0 + 8];
    float4 ya = *(const float4*)&h2s[jrow][kb0];
    float4 yb = *(const float4*)&h2s[jrow][kb0 + 8];
    float v0 = fmaxf(xa.x + ya.x, 0.f), v1 = fmaxf(xa.y + ya.y, 0.f);
    float v2 = fmaxf(xa.z + ya.z, 0.f), v3 = fmaxf(xa.w + ya.w, 0.f);
    float v4 = fmaxf(xb.x + yb.x, 0.f), v5 = fmaxf(xb.y + yb.y, 0.f);
    float v6 = fmaxf(xb.z + yb.z, 0.f), v7 = fmaxf(xb.w + yb.w, 0.f);
    uint4 pk;
    pk.x = (uint)f2h(v0) | ((uint)f2h(v1) << 16);
    pk.y = (uint)f2h(v2) | ((uint)f2h(v3) << 16);
    pk.z = (uint)f2h(v4) | ((uint)f2h(v5) << 16);
    pk.w = (uint)f2h(v6) | ((uint)f2h(v7) << 16);
    f16x8 af = __builtin_bit_cast(f16x8, pk);
    #pragma unroll
    for (int ct = 0; ct < 4; ++ct) {
      uint4 braw = *(const uint4*)&bptr[((ks * 4 + ct) * 64 + l) * 8];
      f16x8 bfr = __builtin_bit_cast(f16x8, braw);
      acc[ct] = __builtin_amdgcn_mfma_f32_32x32x16_f16(af, bfr, acc[ct], 0, 0, 0);
    }
  }

  float b3v = b3[r];
  float* sc_base = scores + (((b * 4 + r) * 128 + it * 8) * 128) + jt * 16;
  float sp[16];
  #pragma unroll
  for (int g = 0; g < 16; ++g) sp[g] = 0.f;
  #pragma unroll
  for (int ct = 0; ct < 4; ++ct) {
    int e = ct * 32 + m31;
    float w3v = w3[r * 128 + e];
    float b2v = b2[r * 128 + e];
    #pragma unroll
    for (int g = 0; g < 16; ++g)
      sp[g] = fmaf(w3v, fmaxf(acc[ct][g] + b2v, 0.f), sp[g]);
  }
  #pragma unroll
  for (int off = 16; off >= 1; off >>= 1)
    #pragma unroll
    for (int g = 0; g < 16; ++g)
      sp[g] += __shfl_xor(sp[g], off, 64);
  if (m31 == 0) {
    int half4 = (l >> 5) << 2;
    #pragma unroll
    for (int g = 0; g < 16; ++g) {
      int p = w * 32 + (g & 3) + 8 * (g >> 2) + half4;
      sc_base[(p >> 4) * 128 + (p & 15)] = sp[g] + b3v;
    }
  }
}

// ---------------- softmax + rel via fp16 MFMA; P rows lane-resident, no LDS ----------------
// Grid 32: (b,r,nh). Wave w owns i-rows [w*32, +32); lane l owns row w*32+(l&31).
__global__ __launch_bounds__(256, 1) void k_softrel_mfma(
    const float* __restrict__ scores, const ushort* __restrict__ f2swz,
    float* __restrict__ all_rel)
{
  int bid = blockIdx.x;
  int nh = bid & 1;
  int r  = (bid >> 1) & 3;
  int b  = bid >> 3;
  int t = threadIdx.x, w = t >> 6, l = t & 63;
  int row = w * 32 + (l & 31);
  const float* srow = scores + ((size_t)(b * 4 + r) * 128 + row) * 128;

  float p[128];
  #pragma unroll
  for (int q = 0; q < 32; ++q) {
    float4 v = *(const float4*)&srow[q * 4];
    p[q * 4 + 0] = v.x; p[q * 4 + 1] = v.y;
    p[q * 4 + 2] = v.z; p[q * 4 + 3] = v.w;
  }
  float m = p[0];
  #pragma unroll
  for (int j = 1; j < 128; ++j) m = fmaxf(m, p[j]);
  float sum = 0.f;
  #pragma unroll
  for (int j = 0; j < 128; ++j) { p[j] = __expf(p[j] - m); sum += p[j]; }
  float inv = 1.f / sum;
  uint preg[64];
  #pragma unroll
  for (int q = 0; q < 64; ++q)
    preg[q] = (uint)f2h(p[2 * q] * inv) | ((uint)f2h(p[2 * q + 1] * inv) << 16);

  f32x16 acc[4];
  #pragma unroll
  for (int c = 0; c < 4; ++c)
    #pragma unroll
    for (int e = 0; e < 16; ++e) acc[c][e] = 0.f;

  int hi2 = (l >> 5) * 2;
  const ushort* bbase = f2swz + (size_t)b * (8 * 8 * 64 * 8);
  #pragma unroll
  for (int ks = 0; ks < 8; ++ks) {
    int b2 = ks * 8 + hi2;
    uint4 pk = make_uint4(preg[b2], preg[b2 + 1], preg[b2 + 4], preg[b2 + 5]);
    f16x8 af = __builtin_bit_cast(f16x8, pk);
    #pragma unroll
    for (int ct = 0; ct < 4; ++ct) {
      uint4 braw = *(const uint4*)&bbase[((ks * 8 + nh * 4 + ct) * 64 + l) * 8];
      f16x8 bfr = __builtin_bit_cast(f16x8, braw);
      acc[ct] = __builtin_amdgcn_mfma_f32_32x32x16_f16(af, bfr, acc[ct], 0, 0, 0);
    }
  }

  // C/D layout: col = ct*32+(l&31), row-in-tile = (g&3)+8*(g>>2)+4*(l>>5)
  int dbase = r * 256 + nh * 128 + (l & 31);
  int half4 = (l >> 5) << 2;
  #pragma unroll
  for (int ct = 0; ct < 4; ++ct)
    #pragma unroll
    for (int g = 0; g < 16; ++g) {
      int i = w * 32 + (g & 3) + 8 * (g >> 2) + half4;
      all_rel[((size_t)(b * 128 + i)) * 1024 + dbase + ct * 32] = acc[ct][g];
    }
}

extern "C" void kernel_launch(void* const* d_in, const int* in_sizes, int n_in,
                              void* d_out, int out_size, void* d_ws, size_t ws_size,
                              hipStream_t stream) {
  const float* f1  = (const float*)d_in[0];
  const float* f2  = (const float*)d_in[1];
  const float* W1  = (const float*)d_in[2];
  const float* b1  = (const float*)d_in[3];
  const float* W2  = (const float*)d_in[4];
  const float* b2  = (const float*)d_in[5];
  const float* w3  = (const float*)d_in[6];
  const float* b3  = (const float*)d_in[7];
  const float* Wa1 = (const float*)d_in[8];
  const float* ba1 = (const float*)d_in[9];
  const float* Wa2 = (const float*)d_in[10];
  const float* ba2 = (const float*)d_in[11];
  float* out = (float*)d_out;
  float* ws = (float*)d_ws;

  float* h1p     = ws;                 // 524288 floats (2MB)
  float* h2      = ws + 524288;        // 524288
  float* scores  = ws + 1048576;       // 262144 (1MB)
  float* all_rel = ws + 1310720;       // 524288 (2MB)
  float* hidden  = ws + 1835008;       // 262144 (1MB); W2swz aliases here (dead by then)
  ushort* W2swz  = (ushort*)(ws + 1835008);
  ushort* f2swz  = (ushort*)(ws + 2097152);   // 131072 ushorts (256KB)
  float* p1 = ws;                      // 4x 512x512 floats = h1p+h2 (dead after scores)
  float* p2 = ws + 1310720;            // 4x 512x256 floats = all_rel (dead after gemm1)

  hipLaunchKernelGGL(k_proj_w2, dim3(4, 4, 34), dim3(256), 0, stream,
                     f1, f2, W1, b1, W2, W2swz, f2swz, h1p, h2);
  hipLaunchKernelGGL(k_scores_mfma, dim3(2048), dim3(256), 0, stream,
                     h1p, h2, W2swz, b2, w3, b3, scores);
  hipLaunchKernelGGL(k_softrel_mfma, dim3(32), dim3(256), 0, stream,
                     scores, f2swz, all_rel);
  hipLaunchKernelGGL((gemm_part<256>), dim3(8, 16, 4), dim3(256), 0, stream,
                     all_rel, Wa1, p1, 1024, 512, 512);
  hipLaunchKernelGGL((reduce_bias_act<4>), dim3(256), dim3(256), 0, stream,
                     p1, ba1, hidden, 512 * 512, 512, 1);
  hipLaunchKernelGGL((gemm_part<128>), dim3(4, 16, 4), dim3(256), 0, stream,
                     hidden, Wa2, p2, 512, 256, 512);
  hipLaunchKernelGGL((reduce_bias_act<4>), dim3(128), dim3(256), 0, stream,
                     p2, ba2, out, 512 * 256, 256, 0);
}

// Round 8
// 78.666 us; speedup vs baseline: 1.2910x; 1.0448x over previous
//
#include <hip/hip_runtime.h>

// Shapes: B=4, N1=N2=128, D=256, R=4, E=D/2=128
// Pipeline:
//   A: h1p/h2 projections (fp16 packed out) + W2/f2 fp16 pre-swizzle  [one kernel]
//   B: scores via fp16 MFMA; A-fragments built with v_pk_add/max_f16 from fp16 LDS
//   C: softmax+rel via fp16 MFMA (P rows lane-resident, 128 x 1-wave blocks)
//   D: final MLP  [fp32 32x64-tile GEMM, split-K x4 + reduce]

typedef _Float16 f16x8 __attribute__((ext_vector_type(8)));
typedef float f32x16 __attribute__((ext_vector_type(16)));

static __device__ __forceinline__ ushort f2h(float f) {
  _Float16 h = (_Float16)f;
  return __builtin_bit_cast(ushort, h);
}
static __device__ __forceinline__ uint pack2(float a, float b) {
  return (uint)f2h(a) | ((uint)f2h(b) << 16);
}
static __device__ __forceinline__ uint pk_add(uint a, uint b) {
  uint r;
  asm("v_pk_add_f16 %0, %1, %2" : "=v"(r) : "v"(a), "v"(b));
  return r;
}
static __device__ __forceinline__ uint pk_relu(uint a) {
  uint r;
  asm("v_pk_max_f16 %0, %1, %2" : "=v"(r) : "v"(a), "v"(0u));
  return r;
}

// ---------------- fp32 32x64-tile GEMM core (micro 2x4, KC=32) ----------------
template<int KBLK>
static __device__ __forceinline__ void gemm32x64_body(
    const float* __restrict__ A, const float* __restrict__ W,
    float* __restrict__ Cout, int K, int N, int rt, int ct, int k0)
{
  int t = threadIdx.x;
  int tm2 = t >> 4;
  int tn4 = t & 15;
  int arow = t >> 3;
  int akq = (t & 7) * 4;
  int bk = t >> 4;
  int bn4 = (t & 15) * 4;
  __shared__ __align__(16) float As[32][33];
  __shared__ __align__(16) float Bs[32][64];

  const float* Ab = A + (size_t)(rt * 32 + arow) * K + k0;
  const float* Wb = W + (size_t)k0 * N + ct * 64 + bn4;

  float4 pa = *(const float4*)&Ab[akq];
  float4 pb0 = *(const float4*)&Wb[(size_t)bk * N];
  float4 pb1 = *(const float4*)&Wb[(size_t)(bk + 16) * N];

  float acc[2][4];
  #pragma unroll
  for (int i = 0; i < 2; ++i)
    #pragma unroll
    for (int j = 0; j < 4; ++j) acc[i][j] = 0.f;

  for (int kc = 0; kc < KBLK; kc += 32) {
    __syncthreads();
    As[akq + 0][arow] = pa.x;
    As[akq + 1][arow] = pa.y;
    As[akq + 2][arow] = pa.z;
    As[akq + 3][arow] = pa.w;
    *(float4*)&Bs[bk][bn4] = pb0;
    *(float4*)&Bs[bk + 16][bn4] = pb1;
    __syncthreads();
    if (kc + 32 < KBLK) {
      pa  = *(const float4*)&Ab[kc + 32 + akq];
      pb0 = *(const float4*)&Wb[(size_t)(kc + 32 + bk) * N];
      pb1 = *(const float4*)&Wb[(size_t)(kc + 32 + bk + 16) * N];
    }
    #pragma unroll
    for (int kk = 0; kk < 32; ++kk) {
      float2 a = *(const float2*)&As[kk][tm2 * 2];
      float4 w = *(const float4*)&Bs[kk][tn4 * 4];
      acc[0][0] = fmaf(a.x, w.x, acc[0][0]); acc[0][1] = fmaf(a.x, w.y, acc[0][1]);
      acc[0][2] = fmaf(a.x, w.z, acc[0][2]); acc[0][3] = fmaf(a.x, w.w, acc[0][3]);
      acc[1][0] = fmaf(a.y, w.x, acc[1][0]); acc[1][1] = fmaf(a.y, w.y, acc[1][1]);
      acc[1][2] = fmaf(a.y, w.z, acc[1][2]); acc[1][3] = fmaf(a.y, w.w, acc[1][3]);
    }
  }

  int col = ct * 64 + tn4 * 4;
  #pragma unroll
  for (int qm = 0; qm < 2; ++qm) {
    int row = rt * 32 + tm2 * 2 + qm;
    float4 ov = make_float4(acc[qm][0], acc[qm][1], acc[qm][2], acc[qm][3]);
    *(float4*)&Cout[(size_t)row * N + col] = ov;
  }
}

template<int KBLK>
__global__ __launch_bounds__(256) void gemm_part(
    const float* __restrict__ A, const float* __restrict__ W,
    float* __restrict__ part, int K, int N, int M)
{
  int kp = blockIdx.z;
  gemm32x64_body<KBLK>(A, W, part + (size_t)kp * M * N, K, N,
                       blockIdx.y, blockIdx.x, kp * KBLK);
}

template<int P>
__global__ __launch_bounds__(256) void reduce_bias_act(
    const float* __restrict__ part, const float* __restrict__ bias,
    float* __restrict__ C, int MN, int N, int act)
{
  int idx4 = (blockIdx.x * 256 + threadIdx.x) * 4;
  if (idx4 >= MN) return;
  float4 s = *(const float4*)&part[idx4];
  #pragma unroll
  for (int p = 1; p < P; ++p) {
    float4 v = *(const float4*)&part[(size_t)p * MN + idx4];
    s.x += v.x; s.y += v.y; s.z += v.z; s.w += v.w;
  }
  float4 bv = *(const float4*)&bias[idx4 & (N - 1)];
  s.x += bv.x; s.y += bv.y; s.z += bv.z; s.w += bv.w;
  if (act) {
    s.x = fmaxf(s.x, 0.f); s.y = fmaxf(s.y, 0.f);
    s.z = fmaxf(s.z, 0.f); s.w = fmaxf(s.w, 0.f);
  }
  *(float4*)&C[idx4] = s;
}

// ---------------- projection (z<32, fp16 out) + W2 swz (z==32) + f2 swz (z==33) ----------------
__global__ __launch_bounds__(256) void k_proj_w2(
    const float* __restrict__ f1, const float* __restrict__ f2,
    const float* __restrict__ W1, const float* __restrict__ b1,
    const float* __restrict__ W2, ushort* __restrict__ W2swz,
    ushort* __restrict__ f2swz,
    ushort* __restrict__ h1p, ushort* __restrict__ h2)
{
  int z = blockIdx.z;
  int t = threadIdx.x;
  __shared__ __align__(16) float As[32][33];
  __shared__ __align__(16) float Bs[32][64];

  if (z == 32) {
    // W2 -> f16 B-fragment order: [r][ks16][ct4][lane][j8]
    int sub = blockIdx.y * 4 + blockIdx.x;
    int r = sub >> 2, ks0 = (sub & 3) * 4;
    int ct = t >> 6, l = t & 63;
    #pragma unroll
    for (int ko = 0; ko < 4; ++ko) {
      int ks = ks0 + ko;
      ushort us[8];
      #pragma unroll
      for (int j = 0; j < 8; ++j) {
        int d = ks * 16 + ((j >> 2) * 8) + ((l >> 5) * 4) + (j & 3);
        int e = ct * 32 + (l & 31);
        us[j] = f2h(W2[(r * 256 + d) * 128 + e]);
      }
      uint4 pk;
      pk.x = (uint)us[0] | ((uint)us[1] << 16);
      pk.y = (uint)us[2] | ((uint)us[3] << 16);
      pk.z = (uint)us[4] | ((uint)us[5] << 16);
      pk.w = (uint)us[6] | ((uint)us[7] << 16);
      *(uint4*)&W2swz[(((r * 16 + ks) * 4 + ct) * 64 + l) * 8] = pk;
    }
    return;
  }
  if (z == 33) {
    // f2 -> f16 B-fragment order: [b][ks8][ctg8][lane][j8]
    int sub = blockIdx.y * 4 + blockIdx.x;
    int w = t >> 6, l = t & 63;
    #pragma unroll
    for (int ko = 0; ko < 4; ++ko) {
      int u = sub * 16 + w * 4 + ko;
      int b = u >> 6, ks = (u >> 3) & 7, ctg = u & 7;
      ushort us[8];
      #pragma unroll
      for (int j = 0; j < 8; ++j) {
        int k = ks * 16 + ((l >> 5) * 4) + (j & 3) + ((j >> 2) * 8);
        int n = ctg * 32 + (l & 31);
        us[j] = f2h(f2[((size_t)b * 128 + k) * 256 + n]);
      }
      uint4 pk;
      pk.x = (uint)us[0] | ((uint)us[1] << 16);
      pk.y = (uint)us[2] | ((uint)us[3] << 16);
      pk.z = (uint)us[4] | ((uint)us[5] << 16);
      pk.w = (uint)us[6] | ((uint)us[7] << 16);
      *(uint4*)&f2swz[(((b * 8 + ks) * 8 + ctg) * 64 + l) * 8] = pk;
    }
    return;
  }

  int half = z >> 4, b = (z >> 2) & 3, r = z & 3;
  int rt = blockIdx.y, ct = blockIdx.x;
  int tm2 = t >> 4, tn4 = t & 15;
  int arow = t >> 3, akq = (t & 7) * 4;
  int bk = t >> 4, bn4 = (t & 15) * 4;

  const float* A = (half ? f2 : f1) + (size_t)b * 128 * 256;
  const float* W = W1 + (size_t)(r * 512 + half * 256) * 256;
  const float* Ab = A + (rt * 32 + arow) * 256;
  const float* Wb = W + ct * 64 + bn4;

  float4 pa = *(const float4*)&Ab[akq];
  float4 pb0 = *(const float4*)&Wb[bk * 256];
  float4 pb1 = *(const float4*)&Wb[(bk + 16) * 256];

  float acc[2][4];
  #pragma unroll
  for (int i = 0; i < 2; ++i)
    #pragma unroll
    for (int j = 0; j < 4; ++j) acc[i][j] = 0.f;

  for (int kc = 0; kc < 256; kc += 32) {
    __syncthreads();
    As[akq + 0][arow] = pa.x;
    As[akq + 1][arow] = pa.y;
    As[akq + 2][arow] = pa.z;
    As[akq + 3][arow] = pa.w;
    *(float4*)&Bs[bk][bn4] = pb0;
    *(float4*)&Bs[bk + 16][bn4] = pb1;
    __syncthreads();
    if (kc + 32 < 256) {
      pa  = *(const float4*)&Ab[kc + 32 + akq];
      pb0 = *(const float4*)&Wb[(kc + 32 + bk) * 256];
      pb1 = *(const float4*)&Wb[(kc + 32 + bk + 16) * 256];
    }
    #pragma unroll
    for (int kk = 0; kk < 32; ++kk) {
      float2 a = *(const float2*)&As[kk][tm2 * 2];
      float4 w = *(const float4*)&Bs[kk][tn4 * 4];
      acc[0][0] = fmaf(a.x, w.x, acc[0][0]); acc[0][1] = fmaf(a.x, w.y, acc[0][1]);
      acc[0][2] = fmaf(a.x, w.z, acc[0][2]); acc[0][3] = fmaf(a.x, w.w, acc[0][3]);
      acc[1][0] = fmaf(a.y, w.x, acc[1][0]); acc[1][1] = fmaf(a.y, w.y, acc[1][1]);
      acc[1][2] = fmaf(a.y, w.z, acc[1][2]); acc[1][3] = fmaf(a.y, w.w, acc[1][3]);
    }
  }

  int col = ct * 64 + tn4 * 4;
  float4 bv;
  if (half) { bv.x = bv.y = bv.z = bv.w = 0.f; }
  else      { bv = *(const float4*)&b1[r * 256 + col]; }
  uint* hu = (uint*)(half ? h2 : h1p);
  #pragma unroll
  for (int qm = 0; qm < 2; ++qm) {
    int row = rt * 32 + tm2 * 2 + qm;
    uint2 pv;
    pv.x = pack2(acc[qm][0] + bv.x, acc[qm][1] + bv.y);
    pv.y = pack2(acc[qm][2] + bv.z, acc[qm][3] + bv.w);
    *(uint2*)&hu[((size_t)((b * 4 + r) * 128 + row)) * 128 + (col >> 1)] = pv;
  }
}

// ---------------- fp16 MFMA scores kernel: packed-f16 A-build ----------------
__global__ __launch_bounds__(256, 4) void k_scores_mfma(
    const ushort* __restrict__ h1p, const ushort* __restrict__ h2,
    const ushort* __restrict__ W2swz, const float* __restrict__ b2,
    const float* __restrict__ w3, const float* __restrict__ b3,
    float* __restrict__ scores)
{
  int bid = blockIdx.x;        // 2048 blocks: b(4) x r(4) x it(16) x jt(8)
  int jt = bid & 7;
  int it = (bid >> 3) & 15;
  int r  = (bid >> 7) & 3;
  int b  = bid >> 9;
  int t = threadIdx.x, w = t >> 6, l = t & 63;
  __shared__ uint h1u[8][132];    // rows as 128 uints (256 halves), pad->132
  __shared__ uint h2u[16][132];

  const uint* h1g = (const uint*)h1p + ((size_t)((b * 4 + r) * 128 + it * 8)) * 128;
  const uint* h2g = (const uint*)h2  + ((size_t)((b * 4 + r) * 128 + jt * 16)) * 128;
  {
    int row = t >> 5, c4 = (t & 31) * 4;
    *(uint4*)&h1u[row][c4] = *(const uint4*)&h1g[row * 128 + c4];
    *(uint4*)&h2u[row][c4] = *(const uint4*)&h2g[row * 128 + c4];
    *(uint4*)&h2u[row + 8][c4] = *(const uint4*)&h2g[(row + 8) * 128 + c4];
  }

  f32x16 acc[4];
  #pragma unroll
  for (int c = 0; c < 4; ++c)
    #pragma unroll
    for (int e = 0; e < 16; ++e) acc[c][e] = 0.f;

  const ushort* bptr = W2swz + r * (16 * 4 * 64 * 8);
  int hi2 = (l >> 5) * 2;          // uint offset within 16-k chunk (0 or 2)
  int m31 = l & 31;
  int jrow = m31 & 15;
  int irow = w * 2 + (m31 >> 4);

  __syncthreads();

  const uint* h1r = &h1u[irow][0];
  const uint* h2r = &h2u[jrow][0];
  for (int ks = 0; ks < 16; ++ks) {
    int u0 = ks * 8 + hi2;
    uint2 xa = *(const uint2*)&h1r[u0];
    uint2 xb = *(const uint2*)&h1r[u0 + 4];
    uint2 ya = *(const uint2*)&h2r[u0];
    uint2 yb = *(const uint2*)&h2r[u0 + 4];
    uint4 pk;
    pk.x = pk_relu(pk_add(xa.x, ya.x));
    pk.y = pk_relu(pk_add(xa.y, ya.y));
    pk.z = pk_relu(pk_add(xb.x, yb.x));
    pk.w = pk_relu(pk_add(xb.y, yb.y));
    f16x8 af = __builtin_bit_cast(f16x8, pk);
    #pragma unroll
    for (int ct = 0; ct < 4; ++ct) {
      uint4 braw = *(const uint4*)&bptr[((ks * 4 + ct) * 64 + l) * 8];
      f16x8 bfr = __builtin_bit_cast(f16x8, braw);
      acc[ct] = __builtin_amdgcn_mfma_f32_32x32x16_f16(af, bfr, acc[ct], 0, 0, 0);
    }
  }

  float b3v = b3[r];
  float* sc_base = scores + (((b * 4 + r) * 128 + it * 8) * 128) + jt * 16;
  float sp[16];
  #pragma unroll
  for (int g = 0; g < 16; ++g) sp[g] = 0.f;
  #pragma unroll
  for (int ct = 0; ct < 4; ++ct) {
    int e = ct * 32 + m31;
    float w3v = w3[r * 128 + e];
    float b2v = b2[r * 128 + e];
    #pragma unroll
    for (int g = 0; g < 16; ++g)
      sp[g] = fmaf(w3v, fmaxf(acc[ct][g] + b2v, 0.f), sp[g]);
  }
  #pragma unroll
  for (int off = 16; off >= 1; off >>= 1)
    #pragma unroll
    for (int g = 0; g < 16; ++g)
      sp[g] += __shfl_xor(sp[g], off, 64);
  if (m31 == 0) {
    int half4 = (l >> 5) << 2;
    #pragma unroll
    for (int g = 0; g < 16; ++g) {
      int p = w * 32 + (g & 3) + 8 * (g >> 2) + half4;
      sc_base[(p >> 4) * 128 + (p & 15)] = sp[g] + b3v;
    }
  }
}

// ---------------- softmax + rel via fp16 MFMA; 128 single-wave blocks ----------------
__global__ __launch_bounds__(64, 1) void k_softrel_mfma(
    const float* __restrict__ scores, const ushort* __restrict__ f2swz,
    float* __restrict__ all_rel)
{
  int bid = blockIdx.x;         // 128: b(4) x r(4) x nh(2) x rowq(4)
  int rowq = bid & 3;
  int nh = (bid >> 2) & 1;
  int r  = (bid >> 3) & 3;
  int b  = bid >> 5;
  int l = threadIdx.x;
  int row = rowq * 32 + (l & 31);
  const float* srow = scores + ((size_t)(b * 4 + r) * 128 + row) * 128;

  float p[128];
  #pragma unroll
  for (int q = 0; q < 32; ++q) {
    float4 v = *(const float4*)&srow[q * 4];
    p[q * 4 + 0] = v.x; p[q * 4 + 1] = v.y;
    p[q * 4 + 2] = v.z; p[q * 4 + 3] = v.w;
  }
  float m = p[0];
  #pragma unroll
  for (int j = 1; j < 128; ++j) m = fmaxf(m, p[j]);
  float sum = 0.f;
  #pragma unroll
  for (int j = 0; j < 128; ++j) { p[j] = __expf(p[j] - m); sum += p[j]; }
  float inv = 1.f / sum;
  uint preg[64];
  #pragma unroll
  for (int q = 0; q < 64; ++q)
    preg[q] = pack2(p[2 * q] * inv, p[2 * q + 1] * inv);

  f32x16 acc[4];
  #pragma unroll
  for (int c = 0; c < 4; ++c)
    #pragma unroll
    for (int e = 0; e < 16; ++e) acc[c][e] = 0.f;

  int hi2 = (l >> 5) * 2;
  const ushort* bbase = f2swz + (size_t)b * (8 * 8 * 64 * 8);
  #pragma unroll
  for (int ks = 0; ks < 8; ++ks) {
    int b2i = ks * 8 + hi2;
    uint4 pk = make_uint4(preg[b2i], preg[b2i + 1], preg[b2i + 4], preg[b2i + 5]);
    f16x8 af = __builtin_bit_cast(f16x8, pk);
    #pragma unroll
    for (int ct = 0; ct < 4; ++ct) {
      uint4 braw = *(const uint4*)&bbase[((ks * 8 + nh * 4 + ct) * 64 + l) * 8];
      f16x8 bfr = __builtin_bit_cast(f16x8, braw);
      acc[ct] = __builtin_amdgcn_mfma_f32_32x32x16_f16(af, bfr, acc[ct], 0, 0, 0);
    }
  }

  int dbase = r * 256 + nh * 128 + (l & 31);
  int half4 = (l >> 5) << 2;
  #pragma unroll
  for (int ct = 0; ct < 4; ++ct)
    #pragma unroll
    for (int g = 0; g < 16; ++g) {
      int i = rowq * 32 + (g & 3) + 8 * (g >> 2) + half4;
      all_rel[((size_t)(b * 128 + i)) * 1024 + dbase + ct * 32] = acc[ct][g];
    }
}

extern "C" void kernel_launch(void* const* d_in, const int* in_sizes, int n_in,
                              void* d_out, int out_size, void* d_ws, size_t ws_size,
                              hipStream_t stream) {
  const float* f1  = (const float*)d_in[0];
  const float* f2  = (const float*)d_in[1];
  const float* W1  = (const float*)d_in[2];
  const float* b1  = (const float*)d_in[3];
  const float* W2  = (const float*)d_in[4];
  const float* b2  = (const float*)d_in[5];
  const float* w3  = (const float*)d_in[6];
  const float* b3  = (const float*)d_in[7];
  const float* Wa1 = (const float*)d_in[8];
  const float* ba1 = (const float*)d_in[9];
  const float* Wa2 = (const float*)d_in[10];
  const float* ba2 = (const float*)d_in[11];
  float* out = (float*)d_out;
  float* ws = (float*)d_ws;

  // Layout (float offsets from ws):
  ushort* h1p    = (ushort*)ws;                  // @0MB, 1MB (524288 halves)
  ushort* h2     = (ushort*)(ws + 262144);       // @1MB, 1MB
  float* scores  = ws + 524288;                  // @2MB, 1MB
  float* all_rel = ws + 1048576;                 // @4MB, 2MB
  float* hidden  = ws + 1572864;                 // @6MB, 1MB
  ushort* W2swz  = (ushort*)(ws + 1835008);      // @7MB, 256KB
  ushort* f2swz  = (ushort*)(ws + 1900544);      // @7.25MB, 256KB
  // Split-K partials alias dead regions (stream-ordered):
  float* p1 = ws;                                // @0..4MB (h1p/h2/scores dead after softrel)
  float* p2 = ws + 1048576;                      // @4..6MB (all_rel dead after gemm1)

  hipLaunchKernelGGL(k_proj_w2, dim3(4, 4, 34), dim3(256), 0, stream,
                     f1, f2, W1, b1, W2, W2swz, f2swz, h1p, h2);
  hipLaunchKernelGGL(k_scores_mfma, dim3(2048), dim3(256), 0, stream,
                     h1p, h2, W2swz, b2, w3, b3, scores);
  hipLaunchKernelGGL(k_softrel_mfma, dim3(128), dim3(64), 0, stream,
                     scores, f2swz, all_rel);
  hipLaunchKernelGGL((gemm_part<256>), dim3(8, 16, 4), dim3(256), 0, stream,
                     all_rel, Wa1, p1, 1024, 512, 512);
  hipLaunchKernelGGL((reduce_bias_act<4>), dim3(256), dim3(256), 0, stream,
                     p1, ba1, hidden, 512 * 512, 512, 1);
  hipLaunchKernelGGL((gemm_part<128>), dim3(4, 16, 4), dim3(256), 0, stream,
                     hidden, Wa2, p2, 512, 256, 512);
  hipLaunchKernelGGL((reduce_bias_act<4>), dim3(128), dim3(256), 0, stream,
                     p2, ba2, out, 512 * 256, 256, 0);
}

// Round 9
// 76.498 us; speedup vs baseline: 1.3276x; 1.0283x over previous
//
#include <hip/hip_runtime.h>

// Shapes: B=4, N1=N2=128, D=256, R=4, E=D/2=128
// Pipeline:
//   A: h1p/h2 projections (fp16 packed out) + W2/f2 fp16 pre-swizzle  [one kernel]
//   B: scores via fp16 MFMA, 2x2 micro-tile per wave (B-fragment reuse x2)
//   C: softmax+rel via fp16 MFMA (P rows lane-resident, 128 x 1-wave blocks)
//   D: final MLP: gemm1 split-K x4 -> gemm2 (fused partial-reduce+bias+relu) -> reduce2

typedef _Float16 f16x8 __attribute__((ext_vector_type(8)));
typedef float f32x16 __attribute__((ext_vector_type(16)));

static __device__ __forceinline__ ushort f2h(float f) {
  _Float16 h = (_Float16)f;
  return __builtin_bit_cast(ushort, h);
}
static __device__ __forceinline__ uint pack2(float a, float b) {
  return (uint)f2h(a) | ((uint)f2h(b) << 16);
}
static __device__ __forceinline__ uint pk_add(uint a, uint b) {
  uint r;
  asm("v_pk_add_f16 %0, %1, %2" : "=v"(r) : "v"(a), "v"(b));
  return r;
}
static __device__ __forceinline__ uint pk_relu(uint a) {
  uint r;
  asm("v_pk_max_f16 %0, %1, %2" : "=v"(r) : "v"(a), "v"(0u));
  return r;
}

// ---------------- fp32 32x64-tile GEMM core (micro 2x4, KC=32) ----------------
template<int KBLK>
static __device__ __forceinline__ void gemm32x64_body(
    const float* __restrict__ A, const float* __restrict__ W,
    float* __restrict__ Cout, int K, int N, int rt, int ct, int k0)
{
  int t = threadIdx.x;
  int tm2 = t >> 4;
  int tn4 = t & 15;
  int arow = t >> 3;
  int akq = (t & 7) * 4;
  int bk = t >> 4;
  int bn4 = (t & 15) * 4;
  __shared__ __align__(16) float As[32][33];
  __shared__ __align__(16) float Bs[32][64];

  const float* Ab = A + (size_t)(rt * 32 + arow) * K + k0;
  const float* Wb = W + (size_t)k0 * N + ct * 64 + bn4;

  float4 pa = *(const float4*)&Ab[akq];
  float4 pb0 = *(const float4*)&Wb[(size_t)bk * N];
  float4 pb1 = *(const float4*)&Wb[(size_t)(bk + 16) * N];

  float acc[2][4];
  #pragma unroll
  for (int i = 0; i < 2; ++i)
    #pragma unroll
    for (int j = 0; j < 4; ++j) acc[i][j] = 0.f;

  for (int kc = 0; kc < KBLK; kc += 32) {
    __syncthreads();
    As[akq + 0][arow] = pa.x;
    As[akq + 1][arow] = pa.y;
    As[akq + 2][arow] = pa.z;
    As[akq + 3][arow] = pa.w;
    *(float4*)&Bs[bk][bn4] = pb0;
    *(float4*)&Bs[bk + 16][bn4] = pb1;
    __syncthreads();
    if (kc + 32 < KBLK) {
      pa  = *(const float4*)&Ab[kc + 32 + akq];
      pb0 = *(const float4*)&Wb[(size_t)(kc + 32 + bk) * N];
      pb1 = *(const float4*)&Wb[(size_t)(kc + 32 + bk + 16) * N];
    }
    #pragma unroll
    for (int kk = 0; kk < 32; ++kk) {
      float2 a = *(const float2*)&As[kk][tm2 * 2];
      float4 w = *(const float4*)&Bs[kk][tn4 * 4];
      acc[0][0] = fmaf(a.x, w.x, acc[0][0]); acc[0][1] = fmaf(a.x, w.y, acc[0][1]);
      acc[0][2] = fmaf(a.x, w.z, acc[0][2]); acc[0][3] = fmaf(a.x, w.w, acc[0][3]);
      acc[1][0] = fmaf(a.y, w.x, acc[1][0]); acc[1][1] = fmaf(a.y, w.y, acc[1][1]);
      acc[1][2] = fmaf(a.y, w.z, acc[1][2]); acc[1][3] = fmaf(a.y, w.w, acc[1][3]);
    }
  }

  int col = ct * 64 + tn4 * 4;
  #pragma unroll
  for (int qm = 0; qm < 2; ++qm) {
    int row = rt * 32 + tm2 * 2 + qm;
    float4 ov = make_float4(acc[qm][0], acc[qm][1], acc[qm][2], acc[qm][3]);
    *(float4*)&Cout[(size_t)row * N + col] = ov;
  }
}

template<int KBLK>
__global__ __launch_bounds__(256) void gemm_part(
    const float* __restrict__ A, const float* __restrict__ W,
    float* __restrict__ part, int K, int N, int M)
{
  int kp = blockIdx.z;
  gemm32x64_body<KBLK>(A, W, part + (size_t)kp * M * N, K, N,
                       blockIdx.y, blockIdx.x, kp * KBLK);
}

// gemm2 with fused reduction of gemm1's 4 partials + ba1 + relu on the A path.
// A[row][k] = relu(ba1[k] + sum_p p1[p][row][k]);  K=512, N=256, KBLK=128.
__global__ __launch_bounds__(256) void gemm2_fused(
    const float* __restrict__ p1, const float* __restrict__ ba1,
    const float* __restrict__ W, float* __restrict__ part)
{
  const int K = 512, N = 256, KBLK = 128;
  int rt = blockIdx.y, ct = blockIdx.x, kp = blockIdx.z;
  int k0 = kp * KBLK;
  float* Cout = part + (size_t)kp * 512 * N;
  int t = threadIdx.x;
  int tm2 = t >> 4;
  int tn4 = t & 15;
  int arow = t >> 3;
  int akq = (t & 7) * 4;
  int bk = t >> 4;
  int bn4 = (t & 15) * 4;
  __shared__ __align__(16) float As[32][33];
  __shared__ __align__(16) float Bs[32][64];

  const float* Ap = p1 + (size_t)(rt * 32 + arow) * K;   // partial 0 row base
  const float* Wb = W + (size_t)k0 * N + ct * 64 + bn4;

  auto loadA = [&](int k) -> float4 {   // k absolute in [0,512)
    float4 s  = *(const float4*)&Ap[k];
    float4 v1 = *(const float4*)&Ap[262144 + k];
    float4 v2 = *(const float4*)&Ap[524288 + k];
    float4 v3 = *(const float4*)&Ap[786432 + k];
    float4 bv = *(const float4*)&ba1[k];
    s.x = fmaxf(s.x + v1.x + v2.x + v3.x + bv.x, 0.f);
    s.y = fmaxf(s.y + v1.y + v2.y + v3.y + bv.y, 0.f);
    s.z = fmaxf(s.z + v1.z + v2.z + v3.z + bv.z, 0.f);
    s.w = fmaxf(s.w + v1.w + v2.w + v3.w + bv.w, 0.f);
    return s;
  };

  float4 pa = loadA(k0 + akq);
  float4 pb0 = *(const float4*)&Wb[(size_t)bk * N];
  float4 pb1 = *(const float4*)&Wb[(size_t)(bk + 16) * N];

  float acc[2][4];
  #pragma unroll
  for (int i = 0; i < 2; ++i)
    #pragma unroll
    for (int j = 0; j < 4; ++j) acc[i][j] = 0.f;

  for (int kc = 0; kc < KBLK; kc += 32) {
    __syncthreads();
    As[akq + 0][arow] = pa.x;
    As[akq + 1][arow] = pa.y;
    As[akq + 2][arow] = pa.z;
    As[akq + 3][arow] = pa.w;
    *(float4*)&Bs[bk][bn4] = pb0;
    *(float4*)&Bs[bk + 16][bn4] = pb1;
    __syncthreads();
    if (kc + 32 < KBLK) {
      pa  = loadA(k0 + kc + 32 + akq);
      pb0 = *(const float4*)&Wb[(size_t)(kc + 32 + bk) * N];
      pb1 = *(const float4*)&Wb[(size_t)(kc + 32 + bk + 16) * N];
    }
    #pragma unroll
    for (int kk = 0; kk < 32; ++kk) {
      float2 a = *(const float2*)&As[kk][tm2 * 2];
      float4 w = *(const float4*)&Bs[kk][tn4 * 4];
      acc[0][0] = fmaf(a.x, w.x, acc[0][0]); acc[0][1] = fmaf(a.x, w.y, acc[0][1]);
      acc[0][2] = fmaf(a.x, w.z, acc[0][2]); acc[0][3] = fmaf(a.x, w.w, acc[0][3]);
      acc[1][0] = fmaf(a.y, w.x, acc[1][0]); acc[1][1] = fmaf(a.y, w.y, acc[1][1]);
      acc[1][2] = fmaf(a.y, w.z, acc[1][2]); acc[1][3] = fmaf(a.y, w.w, acc[1][3]);
    }
  }

  int col = ct * 64 + tn4 * 4;
  #pragma unroll
  for (int qm = 0; qm < 2; ++qm) {
    int row = rt * 32 + tm2 * 2 + qm;
    float4 ov = make_float4(acc[qm][0], acc[qm][1], acc[qm][2], acc[qm][3]);
    *(float4*)&Cout[(size_t)row * N + col] = ov;
  }
}

template<int P>
__global__ __launch_bounds__(256) void reduce_bias_act(
    const float* __restrict__ part, const float* __restrict__ bias,
    float* __restrict__ C, int MN, int N, int act)
{
  int idx4 = (blockIdx.x * 256 + threadIdx.x) * 4;
  if (idx4 >= MN) return;
  float4 s = *(const float4*)&part[idx4];
  #pragma unroll
  for (int p = 1; p < P; ++p) {
    float4 v = *(const float4*)&part[(size_t)p * MN + idx4];
    s.x += v.x; s.y += v.y; s.z += v.z; s.w += v.w;
  }
  float4 bv = *(const float4*)&bias[idx4 & (N - 1)];
  s.x += bv.x; s.y += bv.y; s.z += bv.z; s.w += bv.w;
  if (act) {
    s.x = fmaxf(s.x, 0.f); s.y = fmaxf(s.y, 0.f);
    s.z = fmaxf(s.z, 0.f); s.w = fmaxf(s.w, 0.f);
  }
  *(float4*)&C[idx4] = s;
}

// ---------------- projection (z<32, fp16 out) + W2 swz (z==32) + f2 swz (z==33) ----------------
__global__ __launch_bounds__(256) void k_proj_w2(
    const float* __restrict__ f1, const float* __restrict__ f2,
    const float* __restrict__ W1, const float* __restrict__ b1,
    const float* __restrict__ W2, ushort* __restrict__ W2swz,
    ushort* __restrict__ f2swz,
    ushort* __restrict__ h1p, ushort* __restrict__ h2)
{
  int z = blockIdx.z;
  int t = threadIdx.x;
  __shared__ __align__(16) float As[32][33];
  __shared__ __align__(16) float Bs[32][64];

  if (z == 32) {
    int sub = blockIdx.y * 4 + blockIdx.x;
    int r = sub >> 2, ks0 = (sub & 3) * 4;
    int ct = t >> 6, l = t & 63;
    #pragma unroll
    for (int ko = 0; ko < 4; ++ko) {
      int ks = ks0 + ko;
      ushort us[8];
      #pragma unroll
      for (int j = 0; j < 8; ++j) {
        int d = ks * 16 + ((j >> 2) * 8) + ((l >> 5) * 4) + (j & 3);
        int e = ct * 32 + (l & 31);
        us[j] = f2h(W2[(r * 256 + d) * 128 + e]);
      }
      uint4 pk;
      pk.x = (uint)us[0] | ((uint)us[1] << 16);
      pk.y = (uint)us[2] | ((uint)us[3] << 16);
      pk.z = (uint)us[4] | ((uint)us[5] << 16);
      pk.w = (uint)us[6] | ((uint)us[7] << 16);
      *(uint4*)&W2swz[(((r * 16 + ks) * 4 + ct) * 64 + l) * 8] = pk;
    }
    return;
  }
  if (z == 33) {
    int sub = blockIdx.y * 4 + blockIdx.x;
    int w = t >> 6, l = t & 63;
    #pragma unroll
    for (int ko = 0; ko < 4; ++ko) {
      int u = sub * 16 + w * 4 + ko;
      int b = u >> 6, ks = (u >> 3) & 7, ctg = u & 7;
      ushort us[8];
      #pragma unroll
      for (int j = 0; j < 8; ++j) {
        int k = ks * 16 + ((l >> 5) * 4) + (j & 3) + ((j >> 2) * 8);
        int n = ctg * 32 + (l & 31);
        us[j] = f2h(f2[((size_t)b * 128 + k) * 256 + n]);
      }
      uint4 pk;
      pk.x = (uint)us[0] | ((uint)us[1] << 16);
      pk.y = (uint)us[2] | ((uint)us[3] << 16);
      pk.z = (uint)us[4] | ((uint)us[5] << 16);
      pk.w = (uint)us[6] | ((uint)us[7] << 16);
      *(uint4*)&f2swz[(((b * 8 + ks) * 8 + ctg) * 64 + l) * 8] = pk;
    }
    return;
  }

  int half = z >> 4, b = (z >> 2) & 3, r = z & 3;
  int rt = blockIdx.y, ct = blockIdx.x;
  int tm2 = t >> 4, tn4 = t & 15;
  int arow = t >> 3, akq = (t & 7) * 4;
  int bk = t >> 4, bn4 = (t & 15) * 4;

  const float* A = (half ? f2 : f1) + (size_t)b * 128 * 256;
  const float* W = W1 + (size_t)(r * 512 + half * 256) * 256;
  const float* Ab = A + (rt * 32 + arow) * 256;
  const float* Wb = W + ct * 64 + bn4;

  float4 pa = *(const float4*)&Ab[akq];
  float4 pb0 = *(const float4*)&Wb[bk * 256];
  float4 pb1 = *(const float4*)&Wb[(bk + 16) * 256];

  float acc[2][4];
  #pragma unroll
  for (int i = 0; i < 2; ++i)
    #pragma unroll
    for (int j = 0; j < 4; ++j) acc[i][j] = 0.f;

  for (int kc = 0; kc < 256; kc += 32) {
    __syncthreads();
    As[akq + 0][arow] = pa.x;
    As[akq + 1][arow] = pa.y;
    As[akq + 2][arow] = pa.z;
    As[akq + 3][arow] = pa.w;
    *(float4*)&Bs[bk][bn4] = pb0;
    *(float4*)&Bs[bk + 16][bn4] = pb1;
    __syncthreads();
    if (kc + 32 < 256) {
      pa  = *(const float4*)&Ab[kc + 32 + akq];
      pb0 = *(const float4*)&Wb[(kc + 32 + bk) * 256];
      pb1 = *(const float4*)&Wb[(kc + 32 + bk + 16) * 256];
    }
    #pragma unroll
    for (int kk = 0; kk < 32; ++kk) {
      float2 a = *(const float2*)&As[kk][tm2 * 2];
      float4 w = *(const float4*)&Bs[kk][tn4 * 4];
      acc[0][0] = fmaf(a.x, w.x, acc[0][0]); acc[0][1] = fmaf(a.x, w.y, acc[0][1]);
      acc[0][2] = fmaf(a.x, w.z, acc[0][2]); acc[0][3] = fmaf(a.x, w.w, acc[0][3]);
      acc[1][0] = fmaf(a.y, w.x, acc[1][0]); acc[1][1] = fmaf(a.y, w.y, acc[1][1]);
      acc[1][2] = fmaf(a.y, w.z, acc[1][2]); acc[1][3] = fmaf(a.y, w.w, acc[1][3]);
    }
  }

  int col = ct * 64 + tn4 * 4;
  float4 bv;
  if (half) { bv.x = bv.y = bv.z = bv.w = 0.f; }
  else      { bv = *(const float4*)&b1[r * 256 + col]; }
  uint* hu = (uint*)(half ? h2 : h1p);
  #pragma unroll
  for (int qm = 0; qm < 2; ++qm) {
    int row = rt * 32 + tm2 * 2 + qm;
    uint2 pv;
    pv.x = pack2(acc[qm][0] + bv.x, acc[qm][1] + bv.y);
    pv.y = pack2(acc[qm][2] + bv.z, acc[qm][3] + bv.w);
    *(uint2*)&hu[((size_t)((b * 4 + r) * 128 + row)) * 128 + (col >> 1)] = pv;
  }
}

// ---------------- fp16 MFMA scores: 2x2 micro-tile per wave (B-reuse x2) ----------------
// Block = 8 i-rows x 16 j-rows = 128 pairs = 4 row-tiles of 32. Wave w: row-tile pair
// rtp=(w&1) -> rt{2rtp,2rtp+1}; ct pair ctp=(w>>1) -> ct{2ctp,2ctp+1}. Epilogue combines
// the two e-halves (waves w and w^2) via LDS.
__global__ __launch_bounds__(256, 4) void k_scores_mfma(
    const ushort* __restrict__ h1p, const ushort* __restrict__ h2,
    const ushort* __restrict__ W2swz, const float* __restrict__ b2,
    const float* __restrict__ w3, const float* __restrict__ b3,
    float* __restrict__ scores)
{
  int bid = blockIdx.x;        // 2048 blocks: b(4) x r(4) x it(16) x jt(8)
  int jt = bid & 7;
  int it = (bid >> 3) & 15;
  int r  = (bid >> 7) & 3;
  int b  = bid >> 9;
  int t = threadIdx.x, w = t >> 6, l = t & 63;
  __shared__ uint h1u[8][132];
  __shared__ uint h2u[16][132];
  __shared__ float xch[4][2][2][16];   // [wave][rtl][half][g]

  const uint* h1g = (const uint*)h1p + ((size_t)((b * 4 + r) * 128 + it * 8)) * 128;
  const uint* h2g = (const uint*)h2  + ((size_t)((b * 4 + r) * 128 + jt * 16)) * 128;
  {
    int row = t >> 5, c4 = (t & 31) * 4;
    *(uint4*)&h1u[row][c4] = *(const uint4*)&h1g[row * 128 + c4];
    *(uint4*)&h2u[row][c4] = *(const uint4*)&h2g[row * 128 + c4];
    *(uint4*)&h2u[row + 8][c4] = *(const uint4*)&h2g[(row + 8) * 128 + c4];
  }

  f32x16 acc[2][2];
  #pragma unroll
  for (int i = 0; i < 2; ++i)
    #pragma unroll
    for (int c = 0; c < 2; ++c)
      #pragma unroll
      for (int e = 0; e < 16; ++e) acc[i][c][e] = 0.f;

  int rtp = w & 1, ctp = w >> 1;
  int hi2 = (l >> 5) * 2;
  int m31 = l & 31;
  int jrow = m31 & 15;
  int irow0 = (rtp * 2 + 0) * 2 + (m31 >> 4);
  int irow1 = (rtp * 2 + 1) * 2 + (m31 >> 4);
  const ushort* bptr = W2swz + r * (16 * 4 * 64 * 8);

  __syncthreads();

  const uint* h1r0 = &h1u[irow0][0];
  const uint* h1r1 = &h1u[irow1][0];
  const uint* h2r  = &h2u[jrow][0];
  for (int ks = 0; ks < 16; ++ks) {
    int u0 = ks * 8 + hi2;
    uint2 ya  = *(const uint2*)&h2r[u0];
    uint2 yb  = *(const uint2*)&h2r[u0 + 4];
    uint2 xa0 = *(const uint2*)&h1r0[u0];
    uint2 xb0 = *(const uint2*)&h1r0[u0 + 4];
    uint2 xa1 = *(const uint2*)&h1r1[u0];
    uint2 xb1 = *(const uint2*)&h1r1[u0 + 4];
    uint4 pk0, pk1;
    pk0.x = pk_relu(pk_add(xa0.x, ya.x));
    pk0.y = pk_relu(pk_add(xa0.y, ya.y));
    pk0.z = pk_relu(pk_add(xb0.x, yb.x));
    pk0.w = pk_relu(pk_add(xb0.y, yb.y));
    pk1.x = pk_relu(pk_add(xa1.x, ya.x));
    pk1.y = pk_relu(pk_add(xa1.y, ya.y));
    pk1.z = pk_relu(pk_add(xb1.x, yb.x));
    pk1.w = pk_relu(pk_add(xb1.y, yb.y));
    f16x8 af0 = __builtin_bit_cast(f16x8, pk0);
    f16x8 af1 = __builtin_bit_cast(f16x8, pk1);
    uint4 braw0 = *(const uint4*)&bptr[((ks * 4 + ctp * 2 + 0) * 64 + l) * 8];
    uint4 braw1 = *(const uint4*)&bptr[((ks * 4 + ctp * 2 + 1) * 64 + l) * 8];
    f16x8 bf0 = __builtin_bit_cast(f16x8, braw0);
    f16x8 bf1 = __builtin_bit_cast(f16x8, braw1);
    acc[0][0] = __builtin_amdgcn_mfma_f32_32x32x16_f16(af0, bf0, acc[0][0], 0, 0, 0);
    acc[0][1] = __builtin_amdgcn_mfma_f32_32x32x16_f16(af0, bf1, acc[0][1], 0, 0, 0);
    acc[1][0] = __builtin_amdgcn_mfma_f32_32x32x16_f16(af1, bf0, acc[1][0], 0, 0, 0);
    acc[1][1] = __builtin_amdgcn_mfma_f32_32x32x16_f16(af1, bf1, acc[1][1], 0, 0, 0);
  }

  // Per-wave partial: sp[rtl][g] over this wave's 2 ct (64 e-values).
  float sp[2][16];
  #pragma unroll
  for (int i = 0; i < 2; ++i)
    #pragma unroll
    for (int g = 0; g < 16; ++g) sp[i][g] = 0.f;
  #pragma unroll
  for (int ctl = 0; ctl < 2; ++ctl) {
    int e = (ctp * 2 + ctl) * 32 + m31;
    float w3v = w3[r * 128 + e];
    float b2v = b2[r * 128 + e];
    #pragma unroll
    for (int i = 0; i < 2; ++i)
      #pragma unroll
      for (int g = 0; g < 16; ++g)
        sp[i][g] = fmaf(w3v, fmaxf(acc[i][ctl][g] + b2v, 0.f), sp[i][g]);
  }
  #pragma unroll
  for (int off = 16; off >= 1; off >>= 1)
    #pragma unroll
    for (int i = 0; i < 2; ++i)
      #pragma unroll
      for (int g = 0; g < 16; ++g)
        sp[i][g] += __shfl_xor(sp[i][g], off, 64);
  int hi = l >> 5;
  if (m31 == 0) {
    #pragma unroll
    for (int i = 0; i < 2; ++i)
      #pragma unroll
      for (int g = 0; g < 16; ++g)
        xch[w][i][hi][g] = sp[i][g];
  }
  __syncthreads();
  if (w < 2 && m31 == 0) {
    float b3v = b3[r];
    float* sc_base = scores + (((b * 4 + r) * 128 + it * 8) * 128) + jt * 16;
    #pragma unroll
    for (int i = 0; i < 2; ++i)
      #pragma unroll
      for (int g = 0; g < 16; ++g) {
        float s = xch[w][i][hi][g] + xch[w + 2][i][hi][g] + b3v;
        int p = (w * 2 + i) * 32 + (g & 3) + 8 * (g >> 2) + hi * 4;
        sc_base[(p >> 4) * 128 + (p & 15)] = s;
      }
  }
}

// ---------------- softmax + rel via fp16 MFMA; 128 single-wave blocks ----------------
__global__ __launch_bounds__(64, 1) void k_softrel_mfma(
    const float* __restrict__ scores, const ushort* __restrict__ f2swz,
    float* __restrict__ all_rel)
{
  int bid = blockIdx.x;         // 128: b(4) x r(4) x nh(2) x rowq(4)
  int rowq = bid & 3;
  int nh = (bid >> 2) & 1;
  int r  = (bid >> 3) & 3;
  int b  = bid >> 5;
  int l = threadIdx.x;
  int row = rowq * 32 + (l & 31);
  const float* srow = scores + ((size_t)(b * 4 + r) * 128 + row) * 128;

  float p[128];
  #pragma unroll
  for (int q = 0; q < 32; ++q) {
    float4 v = *(const float4*)&srow[q * 4];
    p[q * 4 + 0] = v.x; p[q * 4 + 1] = v.y;
    p[q * 4 + 2] = v.z; p[q * 4 + 3] = v.w;
  }
  float m = p[0];
  #pragma unroll
  for (int j = 1; j < 128; ++j) m = fmaxf(m, p[j]);
  float sum = 0.f;
  #pragma unroll
  for (int j = 0; j < 128; ++j) { p[j] = __expf(p[j] - m); sum += p[j]; }
  float inv = 1.f / sum;
  uint preg[64];
  #pragma unroll
  for (int q = 0; q < 64; ++q)
    preg[q] = pack2(p[2 * q] * inv, p[2 * q + 1] * inv);

  f32x16 acc[4];
  #pragma unroll
  for (int c = 0; c < 4; ++c)
    #pragma unroll
    for (int e = 0; e < 16; ++e) acc[c][e] = 0.f;

  int hi2 = (l >> 5) * 2;
  const ushort* bbase = f2swz + (size_t)b * (8 * 8 * 64 * 8);
  #pragma unroll
  for (int ks = 0; ks < 8; ++ks) {
    int b2i = ks * 8 + hi2;
    uint4 pk = make_uint4(preg[b2i], preg[b2i + 1], preg[b2i + 4], preg[b2i + 5]);
    f16x8 af = __builtin_bit_cast(f16x8, pk);
    #pragma unroll
    for (int ct = 0; ct < 4; ++ct) {
      uint4 braw = *(const uint4*)&bbase[((ks * 8 + nh * 4 + ct) * 64 + l) * 8];
      f16x8 bfr = __builtin_bit_cast(f16x8, braw);
      acc[ct] = __builtin_amdgcn_mfma_f32_32x32x16_f16(af, bfr, acc[ct], 0, 0, 0);
    }
  }

  int dbase = r * 256 + nh * 128 + (l & 31);
  int half4 = (l >> 5) << 2;
  #pragma unroll
  for (int ct = 0; ct < 4; ++ct)
    #pragma unroll
    for (int g = 0; g < 16; ++g) {
      int i = rowq * 32 + (g & 3) + 8 * (g >> 2) + half4;
      all_rel[((size_t)(b * 128 + i)) * 1024 + dbase + ct * 32] = acc[ct][g];
    }
}

extern "C" void kernel_launch(void* const* d_in, const int* in_sizes, int n_in,
                              void* d_out, int out_size, void* d_ws, size_t ws_size,
                              hipStream_t stream) {
  const float* f1  = (const float*)d_in[0];
  const float* f2  = (const float*)d_in[1];
  const float* W1  = (const float*)d_in[2];
  const float* b1  = (const float*)d_in[3];
  const float* W2  = (const float*)d_in[4];
  const float* b2  = (const float*)d_in[5];
  const float* w3  = (const float*)d_in[6];
  const float* b3  = (const float*)d_in[7];
  const float* Wa1 = (const float*)d_in[8];
  const float* ba1 = (const float*)d_in[9];
  const float* Wa2 = (const float*)d_in[10];
  const float* ba2 = (const float*)d_in[11];
  float* out = (float*)d_out;
  float* ws = (float*)d_ws;

  // Workspace (float offsets; ws is 256MB so no aliasing needed):
  ushort* h1p    = (ushort*)ws;                  // @0MB, 1MB
  ushort* h2     = (ushort*)(ws + 262144);       // @1MB, 1MB
  float* scores  = ws + 524288;                  // @2MB, 1MB
  float* all_rel = ws + 1048576;                 // @4MB, 2MB
  ushort* W2swz  = (ushort*)(ws + 1835008);      // @7MB, 256KB
  ushort* f2swz  = (ushort*)(ws + 1900544);      // @7.25MB, 256KB
  float* p1      = ws + 2097152;                 // @8MB, 4MB (4 x 512x512)
  float* p2      = ws + 3145728;                 // @12MB, 2MB (4 x 512x256)

  hipLaunchKernelGGL(k_proj_w2, dim3(4, 4, 34), dim3(256), 0, stream,
                     f1, f2, W1, b1, W2, W2swz, f2swz, h1p, h2);
  hipLaunchKernelGGL(k_scores_mfma, dim3(2048), dim3(256), 0, stream,
                     h1p, h2, W2swz, b2, w3, b3, scores);
  hipLaunchKernelGGL(k_softrel_mfma, dim3(128), dim3(64), 0, stream,
                     scores, f2swz, all_rel);
  hipLaunchKernelGGL((gemm_part<256>), dim3(8, 16, 4), dim3(256), 0, stream,
                     all_rel, Wa1, p1, 1024, 512, 512);
  hipLaunchKernelGGL(gemm2_fused, dim3(4, 16, 4), dim3(256), 0, stream,
                     p1, ba1, Wa2, p2);
  hipLaunchKernelGGL((reduce_bias_act<4>), dim3(128), dim3(256), 0, stream,
                     p2, ba2, out, 512 * 256, 256, 0);
}